// Round 9
// baseline (238.972 us; speedup 1.0000x reference)
//
#include <hip/hip_runtime.h>

typedef __attribute__((ext_vector_type(8)))  short bf16x8;   // MFMA A/B frag (4 VGPRs)
typedef __attribute__((ext_vector_type(4)))  float f32x4;    // 16x16 C/D frag
typedef __attribute__((ext_vector_type(16))) float f32x16;   // 32x32 C/D frag
typedef __attribute__((ext_vector_type(4)))  unsigned u32x4;

#define Nx 2048
#define CTXx 2049
#define KCAP 2176          // 2049 real keys + 127 pad (34 tiles); pad K rows/V cols ZEROED
#define NTILES 34
#define QSCALE 0.18033688f // 0.125 * log2(e): softmax computed as 2^(S*log2e) = e^S

__device__ __forceinline__ short f2bs(float x){   // float -> bf16 bits (RNE)
    unsigned u = __builtin_bit_cast(unsigned, x);
    u = (u + 0x7fffu + ((u >> 16) & 1u)) >> 16;
    return (short)u;
}
// truncating pack: (hi16 of b)<<16 | (hi16 of a) — 1 v_perm_b32
__device__ __forceinline__ unsigned pack_trunc(float a, float b){
    return __builtin_amdgcn_perm(__builtin_bit_cast(unsigned, b),
                                 __builtin_bit_cast(unsigned, a), 0x07060302u);
}

// ---------------- fused LN1 (blocks 0..2047) + weight prep (2048..2193) ----------------
__global__ void __launch_bounds__(256) ln1_prep_kernel(const float* __restrict__ x,
                                                       const float* __restrict__ g,
                                                       short* __restrict__ xnb,
                                                       const float* __restrict__ Wq,
                                                       const float* __restrict__ Wkv,
                                                       const float* __restrict__ Wout,
                                                       const float* __restrict__ nkv,
                                                       const int* __restrict__ mask,
                                                       short* __restrict__ WcatT,
                                                       short* __restrict__ WoutT,
                                                       short* __restrict__ kb,
                                                       short* __restrict__ vbt,
                                                       short* __restrict__ mvb){
    __shared__ float ls[64][65];
    int t = threadIdx.x;
    if (blockIdx.x < 2048){    // ---- LN1: wave per row, fp32 -> bf16 ----
        int w = t >> 6, lane = t & 63;
        size_t row = (size_t)blockIdx.x * 4 + w;
        const float* xr = x + row * 512 + lane * 8;
        float4 a = *(const float4*)xr;
        float4 b = *(const float4*)(xr + 4);
        float s = a.x + a.y + a.z + a.w + b.x + b.y + b.z + b.w;
        float q = a.x*a.x + a.y*a.y + a.z*a.z + a.w*a.w
                + b.x*b.x + b.y*b.y + b.z*b.z + b.w*b.w;
        #pragma unroll
        for (int m = 1; m < 64; m <<= 1){ s += __shfl_xor(s, m, 64); q += __shfl_xor(q, m, 64); }
        float mu  = s * (1.f / 512.f);
        float var = fmaxf(q * (1.f / 512.f) - mu * mu, 0.f);
        float r   = rsqrtf(var + 1e-5f);
        const float* gr = g + lane * 8;
        float4 g0 = *(const float4*)gr;
        float4 g1 = *(const float4*)(gr + 4);
        bf16x8 o;
        o[0] = f2bs((a.x - mu) * r * g0.x); o[1] = f2bs((a.y - mu) * r * g0.y);
        o[2] = f2bs((a.z - mu) * r * g0.z); o[3] = f2bs((a.w - mu) * r * g0.w);
        o[4] = f2bs((b.x - mu) * r * g1.x); o[5] = f2bs((b.y - mu) * r * g1.y);
        o[6] = f2bs((b.z - mu) * r * g1.z); o[7] = f2bs((b.w - mu) * r * g1.w);
        *(bf16x8*)(xnb + row * 512 + lane * 8) = o;
        return;
    }
    int bid = blockIdx.x - 2048;
    if (bid == 144){   // null K/V row (key 0, all batches)
        int b = t >> 6, d = t & 63;
        kb[((size_t)b * KCAP) * 64 + d] = f2bs(nkv[d]);
        vbt[((size_t)b * 64 + d) * KCAP + 0] = f2bs(nkv[64 + d]);
        return;
    }
    if (bid == 145){   // zero K/V pads + build bf16 mask frags (B-operand order)
        int b = t >> 6, i6 = t & 63;
        // kb pad rows 2049..2175 -> 0 (pad S = q.0 = 0, P = 1, finite; excluded by V=0 & mv=0)
        for (int rr = 2049 + i6; rr < KCAP; rr += 64){
            short* kr = kb + ((size_t)b * KCAP + rr) * 64;
            #pragma unroll
            for (int d = 0; d < 64; d += 8) *(int4*)(kr + d) = make_int4(0, 0, 0, 0);
        }
        {   // vbt pad cols 2049..2175 -> 0 (masked-by-zero V)
            short* vr = vbt + ((size_t)b * 64 + i6) * KCAP;
            for (int k = 2049; k < KCAP; k++) vr[k] = 0;
        }
        // mv frag order: lane = s*16 + hb*8 + j; key(s,hb,j) = (s>>1)*32 + 8*g + 4*hb + (j&3)
        int lane = t & 63;
        int s = lane >> 4, hb = (lane >> 3) & 1, j = lane & 7;
        int g = (j < 4) ? ((2 * s) & 3) : ((2 * s + 1) & 3);
        int kl = (s >> 1) * 32 + 8 * g + 4 * hb + (j & 3);
        const int* mrow = mask + b * Nx;
        for (int wi = 0; wi < NTILES; wi++){
            int gk = wi * 64 + kl;    // global key (0 = null key, always valid)
            int ok = (gk == 0) ? 1 : ((gk <= Nx) ? mrow[gk - 1] : 0);
            mvb[(size_t)b * KCAP + wi * 64 + lane] = ok ? (short)0x3F80 : (short)0;
        }
        return;
    }
    // ---- LDS-tiled transpose: 0..79 WcatT (640x512), 80..143 WoutT (512x512) ----
    bool isOut = (bid >= 80);
    int b2 = isOut ? bid - 80 : bid;
    int ntile = isOut ? (b2 & 7) : (b2 % 10);
    int ktile = isOut ? (b2 >> 3) : (b2 / 10);
    int n0 = ntile * 64, k0 = ktile * 64;
    #pragma unroll
    for (int rr = 0; rr < 64; rr += 16){   // coalesced float4 reads of W[k][n]
        int r = rr + (t >> 4), c = (t & 15) * 4;
        float4 v;
        if (isOut)            v = *(const float4*)(Wout + (size_t)(k0 + r) * 512 + n0 + c);
        else if (n0 < 512)    v = *(const float4*)(Wq   + (size_t)(k0 + r) * 512 + n0 + c);
        else                  v = *(const float4*)(Wkv  + (size_t)(k0 + r) * 128 + (n0 - 512) + c);
        ls[c + 0][r] = v.x; ls[c + 1][r] = v.y; ls[c + 2][r] = v.z; ls[c + 3][r] = v.w;
    }
    __syncthreads();
    int rn = t >> 2, kc = (t & 3) * 16;    // coalesced 32B bf16 writes of W^T[n][k]
    short tmp[16];
    #pragma unroll
    for (int j = 0; j < 16; j++) tmp[j] = f2bs(ls[rn][kc + j]);
    short* dst = (isOut ? WoutT : WcatT) + (size_t)(n0 + rn) * 512 + k0 + kc;
    *(int4*)dst       = *(int4*)&tmp[0];
    *(int4*)(dst + 8) = *(int4*)&tmp[8];
}

// ---------------- LN2: fp32 in -> fp32 out, wave per row ----------------
__global__ void __launch_bounds__(256) ln2_kernel(const float* __restrict__ z,
                                                  const float* __restrict__ g,
                                                  float* __restrict__ out){
    int w = threadIdx.x >> 6, lane = threadIdx.x & 63;
    size_t row = (size_t)blockIdx.x * 4 + w;
    const float* xr = z + row * 512 + lane * 8;
    float4 a = *(const float4*)xr;
    float4 b = *(const float4*)(xr + 4);
    float s = a.x + a.y + a.z + a.w + b.x + b.y + b.z + b.w;
    float q = a.x*a.x + a.y*a.y + a.z*a.z + a.w*a.w
            + b.x*b.x + b.y*b.y + b.z*b.z + b.w*b.w;
    #pragma unroll
    for (int m = 1; m < 64; m <<= 1){ s += __shfl_xor(s, m, 64); q += __shfl_xor(q, m, 64); }
    float mu  = s * (1.f / 512.f);
    float var = fmaxf(q * (1.f / 512.f) - mu * mu, 0.f);
    float r   = rsqrtf(var + 1e-5f);
    const float* gr = g + lane * 8;
    float4 g0 = *(const float4*)gr;
    float4 g1 = *(const float4*)(gr + 4);
    float4 o0, o1;
    o0.x = (a.x - mu) * r * g0.x; o0.y = (a.y - mu) * r * g0.y;
    o0.z = (a.z - mu) * r * g0.z; o0.w = (a.w - mu) * r * g0.w;
    o1.x = (b.x - mu) * r * g1.x; o1.y = (b.y - mu) * r * g1.y;
    o1.z = (b.z - mu) * r * g1.z; o1.w = (b.w - mu) * r * g1.w;
    float* op = out + row * 512 + lane * 8;
    *(float4*)op = o0; *(float4*)(op + 4) = o1;
}

// ---------------- GEMM QKV: 128x160 tile, grid (4,64) = 256 blocks ----------------
// C = xn @ [Wq|Wkv] (N=640): q-scale(incl log2e) + K scatter + V^T scatter epilogue (bf16)
// V epilogue applies the key mask (masked keys' V cols = 0) — removes masking from attn.
__global__ void __launch_bounds__(256, 1) gemm_qkv(const short* __restrict__ A,
                                                   const short* __restrict__ BwT,
                                                   const int* __restrict__ mask,
                                                   short* __restrict__ qb,
                                                   short* __restrict__ kb,
                                                   short* __restrict__ vbt){
    __shared__ short As[2][128][72];   // [buf][m][k]
    __shared__ short Bs[2][160][72];   // [buf][n][k]
    int t = threadIdx.x;
    int lane = t & 63, w = t >> 6;
    int l16 = lane & 15, quad = lane >> 4;
    int wm = w & 1, wn = w >> 1;
    int row0 = blockIdx.y * 128, col0 = blockIdx.x * 160;
    f32x4 acc[4][5];
    #pragma unroll
    for (int i = 0; i < 4; i++)
        #pragma unroll
        for (int j = 0; j < 5; j++) acc[i][j] = (f32x4){0.f, 0.f, 0.f, 0.f};
    int ar = t >> 1, ak = (t & 1) * 32;
    const short* ap = A + (size_t)(row0 + ar) * 512 + ak;
    int4 a0 = *(const int4*)(ap);      int4 a1 = *(const int4*)(ap + 8);
    int4 a2 = *(const int4*)(ap + 16); int4 a3 = *(const int4*)(ap + 24);
    // B staging: 160 rows x 64 k = 1280 int4, 5 per thread, coalesced (idx = pass*256 + t)
    int4 pb[5];
    int brow[5], bseg[5];
    #pragma unroll
    for (int ps = 0; ps < 5; ps++){
        int idx = ps * 256 + t;
        brow[ps] = idx >> 3; bseg[ps] = (idx & 7) * 8;
        pb[ps] = *(const int4*)(BwT + (size_t)(col0 + brow[ps]) * 512 + bseg[ps]);
    }
    int p = 0;
    for (int k0 = 0; k0 < 512; k0 += 64){
        *(int4*)&As[p][ar][ak]      = a0;
        *(int4*)&As[p][ar][ak + 8]  = a1;
        *(int4*)&As[p][ar][ak + 16] = a2;
        *(int4*)&As[p][ar][ak + 24] = a3;
        #pragma unroll
        for (int ps = 0; ps < 5; ps++)
            *(int4*)&Bs[p][brow[ps]][bseg[ps]] = pb[ps];
        __syncthreads();
        int kn = k0 + 64;
        if (kn < 512){   // prefetch next k-slab while computing this one
            a0 = *(const int4*)(ap + kn);      a1 = *(const int4*)(ap + kn + 8);
            a2 = *(const int4*)(ap + kn + 16); a3 = *(const int4*)(ap + kn + 24);
            #pragma unroll
            for (int ps = 0; ps < 5; ps++)
                pb[ps] = *(const int4*)(BwT + (size_t)(col0 + brow[ps]) * 512 + kn + bseg[ps]);
        }
        #pragma unroll
        for (int ks = 0; ks < 2; ks++){
            bf16x8 af[4], bfr[5];
            #pragma unroll
            for (int mt = 0; mt < 4; mt++)
                af[mt] = *(const bf16x8*)&As[p][wm * 64 + mt * 16 + l16][ks * 32 + quad * 8];
            #pragma unroll
            for (int nt = 0; nt < 5; nt++)
                bfr[nt] = *(const bf16x8*)&Bs[p][wn * 80 + nt * 16 + l16][ks * 32 + quad * 8];
            #pragma unroll
            for (int mt = 0; mt < 4; mt++)
                #pragma unroll
                for (int nt = 0; nt < 5; nt++)
                    acc[mt][nt] = __builtin_amdgcn_mfma_f32_16x16x32_bf16(af[mt], bfr[nt], acc[mt][nt], 0, 0, 0);
        }
        p ^= 1;
    }
    #pragma unroll
    for (int mt = 0; mt < 4; mt++)
        #pragma unroll
        for (int nt = 0; nt < 5; nt++)
            #pragma unroll
            for (int r = 0; r < 4; r++){
                int row = row0 + wm * 64 + mt * 16 + quad * 4 + r;
                int col = col0 + wn * 80 + nt * 16 + l16;
                float v = acc[mt][nt][r];
                int bb = row >> 11, ii = row & 2047;
                if (col < 512){
                    qb[(size_t)row * 512 + col] = f2bs(v * QSCALE);
                } else if (col < 576){
                    kb[((size_t)bb * KCAP + ii + 1) * 64 + (col - 512)] = f2bs(v);
                } else {
                    if (!mask[bb * Nx + ii]) v = 0.f;   // masked key -> zero V column
                    vbt[((size_t)bb * 64 + (col - 576)) * KCAP + ii + 1] = f2bs(v);
                }
            }
}

// ---------------- GEMM OUT: 128x128 tile, grid (4,64) = 256 blocks, fp32 out ------
__global__ void __launch_bounds__(256, 2) gemm_out(const short* __restrict__ A,
                                                   const short* __restrict__ BwT,
                                                   float* __restrict__ C){
    __shared__ short As[2][128][72];
    __shared__ short Bs[2][128][72];
    int t = threadIdx.x;
    int lane = t & 63, w = t >> 6;
    int l16 = lane & 15, quad = lane >> 4;
    int wm = w & 1, wn = w >> 1;
    int row0 = blockIdx.y * 128, col0 = blockIdx.x * 128;
    f32x4 acc[4][4];
    #pragma unroll
    for (int i = 0; i < 4; i++)
        #pragma unroll
        for (int j = 0; j < 4; j++) acc[i][j] = (f32x4){0.f, 0.f, 0.f, 0.f};
    int ar = t >> 1, ak = (t & 1) * 32;
    const short* ap = A   + (size_t)(row0 + ar) * 512 + ak;
    const short* bp = BwT + (size_t)(col0 + ar) * 512 + ak;
    int4 a0 = *(const int4*)(ap);      int4 a1 = *(const int4*)(ap + 8);
    int4 a2 = *(const int4*)(ap + 16); int4 a3 = *(const int4*)(ap + 24);
    int4 b0 = *(const int4*)(bp);      int4 b1 = *(const int4*)(bp + 8);
    int4 b2 = *(const int4*)(bp + 16); int4 b3 = *(const int4*)(bp + 24);
    int p = 0;
    for (int k0 = 0; k0 < 512; k0 += 64){
        *(int4*)&As[p][ar][ak]      = a0;
        *(int4*)&As[p][ar][ak + 8]  = a1;
        *(int4*)&As[p][ar][ak + 16] = a2;
        *(int4*)&As[p][ar][ak + 24] = a3;
        *(int4*)&Bs[p][ar][ak]      = b0;
        *(int4*)&Bs[p][ar][ak + 8]  = b1;
        *(int4*)&Bs[p][ar][ak + 16] = b2;
        *(int4*)&Bs[p][ar][ak + 24] = b3;
        __syncthreads();
        int kn = k0 + 64;
        if (kn < 512){
            a0 = *(const int4*)(ap + kn);      a1 = *(const int4*)(ap + kn + 8);
            a2 = *(const int4*)(ap + kn + 16); a3 = *(const int4*)(ap + kn + 24);
            b0 = *(const int4*)(bp + kn);      b1 = *(const int4*)(bp + kn + 8);
            b2 = *(const int4*)(bp + kn + 16); b3 = *(const int4*)(bp + kn + 24);
        }
        #pragma unroll
        for (int ks = 0; ks < 2; ks++){
            bf16x8 af[4], bfr[4];
            #pragma unroll
            for (int mt = 0; mt < 4; mt++)
                af[mt] = *(const bf16x8*)&As[p][wm * 64 + mt * 16 + l16][ks * 32 + quad * 8];
            #pragma unroll
            for (int nt = 0; nt < 4; nt++)
                bfr[nt] = *(const bf16x8*)&Bs[p][wn * 64 + nt * 16 + l16][ks * 32 + quad * 8];
            #pragma unroll
            for (int mt = 0; mt < 4; mt++)
                #pragma unroll
                for (int nt = 0; nt < 4; nt++)
                    acc[mt][nt] = __builtin_amdgcn_mfma_f32_16x16x32_bf16(af[mt], bfr[nt], acc[mt][nt], 0, 0, 0);
        }
        p ^= 1;
    }
    #pragma unroll
    for (int mt = 0; mt < 4; mt++)
        #pragma unroll
        for (int nt = 0; nt < 4; nt++)
            #pragma unroll
            for (int r = 0; r < 4; r++){
                int row = row0 + wm * 64 + mt * 16 + quad * 4 + r;
                int col = col0 + wn * 64 + nt * 16 + l16;
                C[(size_t)row * 512 + col] = acc[mt][nt][r];
            }
}

// ---------------- MFMA attention v11: in-block key-split, 8 waves, 4 waves/SIMD ----------
// Grid (128 row-tiles, 4 batches), block 512 = 8 waves. Waves 0-3 (half 0) process 17 tiles
// starting at off; waves 4-7 (half 1) the other 17 starting at off+17 (order commutative:
// no-max softmax). Each half has its own double-buffered K/V staging set (73.7 KB total ->
// 2 blocks/CU = 16 waves/CU = 4 waves/SIMD, 2x v10's concurrency for latency hiding).
// KCAP=2176: tile 33 is all-pad (K=0 -> P=1, V=0, mv=0 -> contributes exactly 0).
// Final combine: half 1 writes lacc/oacc to LDS (stride-49 pad), half 0 sums + stores.
__global__ void __launch_bounds__(512, 4) attn_kernel(const short* __restrict__ qb,
                                                      const short* __restrict__ kb,
                                                      const short* __restrict__ vbt,
                                                      const short* __restrict__ mvb,
                                                      short* __restrict__ ob){
    __shared__ short smem[36864];   // 73.7 KB: K = [half][buf][64][72], V = +18432 same layout
    int t = threadIdx.x;
    int lane = t & 63, w = t >> 6;          // w 0..7
    int half = w >> 2, w4 = w & 3;
    int n32 = lane & 31, hb = lane >> 5;
    int b = blockIdx.y, i0 = blockIdx.x * 16;
    int head = 2 * w4 + (n32 >> 4), row = i0 + (n32 & 15);
    // Q frags (B-operand): B[k=8hb+j][n=n32]
    bf16x8 qf[4];
    {
        const short* qp = qb + ((size_t)(b * Nx + row)) * 512 + head * 64 + hb * 8;
        #pragma unroll
        for (int ks = 0; ks < 4; ks++) qf[ks] = *(const bf16x8*)(qp + ks * 16);
    }
    f32x16 oacc[2], lacc;
    #pragma unroll
    for (int j = 0; j < 16; j++){ oacc[0][j] = 0.f; oacc[1][j] = 0.f; lacc[j] = 0.f; }

    int th = t & 255;                        // index within half (4 waves stage one tile)
    int skey = th >> 2, sd = (th & 3) * 16;  // K staging: 64 keys x 64 d
    int vd   = th >> 2, vk = (th & 3) * 16;  // V staging: 64 d x 64 keys
    short* Kb = smem +         (half * 2) * 4608;          // [buf][64][72] per half
    short* Vb = smem + 18432 + (half * 2) * 4608;
    const short* kgp = kb  + (size_t)b * KCAP * 64 + skey * 64 + sd;
    const short* vgp = vbt + ((size_t)b * 64 + vd) * KCAP + vk;
    const short* mvq = mvb + (size_t)b * KCAP + hb * 8;    // mask frags, B-operand order

    // per-block stagger + per-half split: half 0 tiles off..off+16, half 1 off+17..off+33
    int off = (blockIdx.x + 8 * blockIdx.y) % NTILES;
    int jt = off + (half ? 17 : 0); if (jt >= NTILES) jt -= NTILES;

    // prefetch first tile
    int4 pk0 = *(const int4*)(kgp + (size_t)jt * 4096);
    int4 pk1 = *(const int4*)(kgp + (size_t)jt * 4096 + 8);
    int4 pv0 = *(const int4*)(vgp + jt * 64);
    int4 pv1 = *(const int4*)(vgp + jt * 64 + 8);

    int p = 0;
    for (int it = 0; it < 17; ++it){
        short* Ksp = Kb + p * 4608;
        short* Vtp = Vb + p * 4608;
        *(int4*)&Ksp[skey * 72 + sd]     = pk0;
        *(int4*)&Ksp[skey * 72 + sd + 8] = pk1;
        // bit2<->bit3 key permutation == swap middle dwords of the two int4s
        *(int4*)&Vtp[vd * 72 + vk]       = make_int4(pv0.x, pv0.y, pv1.x, pv1.y);
        *(int4*)&Vtp[vd * 72 + vk + 8]   = make_int4(pv0.z, pv0.w, pv1.z, pv1.w);
        __syncthreads();
        // mask frags for THIS tile
        bf16x8 mvf[4];
        #pragma unroll
        for (int s = 0; s < 4; s++) mvf[s] = *(const bf16x8*)(mvq + jt * 64 + s * 16);
        int jn = jt + 1; if (jn == NTILES) jn = 0;   // next tile in rotated order
        // prefetch next tile into regs (hides under compute; last iter's is unused but safe)
        pk0 = *(const int4*)(kgp + (size_t)jn * 4096);
        pk1 = *(const int4*)(kgp + (size_t)jn * 4096 + 8);
        pv0 = *(const int4*)(vgp + jn * 64);
        pv1 = *(const int4*)(vgp + jn * 64 + 8);
        // S^T = K.Q^T from LDS K frags
        f32x16 sf[2];
        #pragma unroll
        for (int i = 0; i < 2; i++)
            #pragma unroll
            for (int j = 0; j < 16; j++) sf[i][j] = 0.f;
        __builtin_amdgcn_s_setprio(1);
        #pragma unroll
        for (int ks = 0; ks < 4; ks++){
            #pragma unroll
            for (int kt = 0; kt < 2; kt++){
                bf16x8 kf = *(const bf16x8*)&Ksp[(kt * 32 + n32) * 72 + ks * 16 + hb * 8];
                sf[kt] = __builtin_amdgcn_mfma_f32_32x32x16_bf16(kf, qf[ks], sf[kt], 0, 0, 0);
            }
        }
        __builtin_amdgcn_s_setprio(0);
        // exp2 + truncating pack — NO masking (handled by zeroed V + maskvec L)
        unsigned pg[8][2];
        #pragma unroll
        for (int kt = 0; kt < 2; kt++){
            #pragma unroll
            for (int g4 = 0; g4 < 4; g4++){
                float pr[4];
                #pragma unroll
                for (int tt = 0; tt < 4; tt++)
                    pr[tt] = __builtin_amdgcn_exp2f(sf[kt][g4 * 4 + tt]);
                pg[kt * 4 + g4][0] = pack_trunc(pr[0], pr[1]);
                pg[kt * 4 + g4][1] = pack_trunc(pr[2], pr[3]);
            }
        }
        // PV + masked L: pa lane-local (V pre-permuted); lacc rows align with oacc rows
        __builtin_amdgcn_s_setprio(1);
        #pragma unroll
        for (int s = 0; s < 4; s++){
            bf16x8 pa = __builtin_bit_cast(bf16x8,
                (u32x4){pg[2 * s][0], pg[2 * s][1], pg[2 * s + 1][0], pg[2 * s + 1][1]});
            lacc = __builtin_amdgcn_mfma_f32_32x32x16_bf16(pa, mvf[s], lacc, 0, 0, 0);
            #pragma unroll
            for (int nt = 0; nt < 2; nt++){
                bf16x8 vf = *(const bf16x8*)&Vtp[(nt * 32 + n32) * 72 + s * 16 + hb * 8];
                oacc[nt] = __builtin_amdgcn_mfma_f32_32x32x16_bf16(pa, vf, oacc[nt], 0, 0, 0);
            }
        }
        __builtin_amdgcn_s_setprio(0);
        p ^= 1;
        jt = jn;
    }
    // ---- combine halves: half 1 -> LDS (stride 49 to dodge bank conflicts), half 0 sums ----
    __syncthreads();                       // all compute done; staging buffers now dead
    float* cm = (float*)smem;              // 18432 floats available; need 256*49 = 12544
    int base = (w4 * 64 + lane) * 49;
    if (half){
        #pragma unroll
        for (int r = 0; r < 16; r++){
            cm[base + r]      = lacc[r];
            cm[base + 16 + r] = oacc[0][r];
            cm[base + 32 + r] = oacc[1][r];
        }
    }
    __syncthreads();
    if (!half){
        #pragma unroll
        for (int r = 0; r < 16; r++){
            lacc[r]    += cm[base + r];
            oacc[0][r] += cm[base + 16 + r];
            oacc[1][r] += cm[base + 32 + r];
        }
        // normalize + store: reg r of lacc holds L for the same (head,row) as reg r of oacc
        #pragma unroll
        for (int r = 0; r < 16; r++){
            float linv = 1.f / lacc[r];
            int hr = (r & 3) + 8 * (r >> 2) + 4 * hb;
            int grow = i0 + (hr & 15);
            int ghead = 2 * w4 + (hr >> 4);
            short* op = ob + ((size_t)(b * Nx + grow)) * 512 + ghead * 64 + n32;
            op[0]  = f2bs(oacc[0][r] * linv);
            op[32] = f2bs(oacc[1][r] * linv);
        }
    }
}

extern "C" void kernel_launch(void* const* d_in, const int* in_sizes, int n_in,
                              void* d_out, int out_size, void* d_ws, size_t ws_size,
                              hipStream_t stream){
    const float* x     = (const float*)d_in[0];
    const int*   mask  = (const int*)  d_in[1];
    const float* gamma = (const float*)d_in[2];
    const float* Wq    = (const float*)d_in[3];
    const float* Wkv   = (const float*)d_in[4];
    const float* nkv   = (const float*)d_in[5];
    const float* Wout  = (const float*)d_in[6];
    const float* og    = (const float*)d_in[7];
    float* out = (float*)d_out;

    short* xnb   = (short*)d_ws;                 // 4194304 shorts
    short* qb    = xnb + (size_t)4194304;        // 4194304
    short* kb    = qb  + (size_t)4194304;        // 4*KCAP*64 = 557056 (pads zeroed)
    short* vbt   = kb  + (size_t)557056;         // 557056 (pads zeroed)
    short* ob    = vbt + (size_t)557056;         // 4194304
    short* WcatT = ob  + (size_t)4194304;        // 327680
    short* WoutT = WcatT + (size_t)327680;       // 262144
    short* mvb   = WoutT + (size_t)262144;       // 4*KCAP = 8704 (bf16 mask frags)
    float* zb    = (float*)d_ws;                 // aliases xnb+qb (both dead by gemm_out)

    ln1_prep_kernel<<<2194, 256, 0, stream>>>(x, gamma, xnb, Wq, Wkv, Wout, nkv, mask,
                                              WcatT, WoutT, kb, vbt, mvb);
    gemm_qkv    <<<dim3(4, 64), 256, 0, stream>>>(xnb, WcatT, mask, qb, kb, vbt);
    attn_kernel <<<dim3(128, 4), 512, 0, stream>>>(qb, kb, vbt, mvb, ob);
    gemm_out    <<<dim3(4, 64), 256, 0, stream>>>(ob, WoutT, zb);
    ln2_kernel  <<<2048, 256, 0, stream>>>(zb, og, out);
}

// Round 15
// 217.116 us; speedup vs baseline: 1.1007x; 1.1007x over previous
//
#include <hip/hip_runtime.h>

typedef __attribute__((ext_vector_type(8)))  short bf16x8;   // MFMA A/B frag (4 VGPRs)
typedef __attribute__((ext_vector_type(4)))  float f32x4;    // 16x16 C/D frag
typedef __attribute__((ext_vector_type(16))) float f32x16;   // 32x32 C/D frag
typedef __attribute__((ext_vector_type(4)))  unsigned u32x4;

#define Nx 2048
#define CTXx 2049
#define KCAP 2176          // 2049 real keys + 127 pad (34 tiles); pad K rows/V cols ZEROED
#define NTILES 34
#define QSCALE 0.18033688f // 0.125 * log2(e): softmax computed as 2^(S*log2e) = e^S

__device__ __forceinline__ short f2bs(float x){   // float -> bf16 bits (RNE)
    unsigned u = __builtin_bit_cast(unsigned, x);
    u = (u + 0x7fffu + ((u >> 16) & 1u)) >> 16;
    return (short)u;
}
// truncating pack: (hi16 of b)<<16 | (hi16 of a) — 1 v_perm_b32
__device__ __forceinline__ unsigned pack_trunc(float a, float b){
    return __builtin_amdgcn_perm(__builtin_bit_cast(unsigned, b),
                                 __builtin_bit_cast(unsigned, a), 0x07060302u);
}

// ---------------- fused LN1 (blocks 0..2047) + weight prep (2048..2193) ----------------
__global__ void __launch_bounds__(256) ln1_prep_kernel(const float* __restrict__ x,
                                                       const float* __restrict__ g,
                                                       short* __restrict__ xnb,
                                                       const float* __restrict__ Wq,
                                                       const float* __restrict__ Wkv,
                                                       const float* __restrict__ Wout,
                                                       const float* __restrict__ nkv,
                                                       const int* __restrict__ mask,
                                                       short* __restrict__ WcatT,
                                                       short* __restrict__ WoutT,
                                                       short* __restrict__ kb,
                                                       short* __restrict__ vbt,
                                                       short* __restrict__ mvb){
    __shared__ float ls[64][65];
    int t = threadIdx.x;
    if (blockIdx.x < 2048){    // ---- LN1: wave per row, fp32 -> bf16 ----
        int w = t >> 6, lane = t & 63;
        size_t row = (size_t)blockIdx.x * 4 + w;
        const float* xr = x + row * 512 + lane * 8;
        float4 a = *(const float4*)xr;
        float4 b = *(const float4*)(xr + 4);
        float s = a.x + a.y + a.z + a.w + b.x + b.y + b.z + b.w;
        float q = a.x*a.x + a.y*a.y + a.z*a.z + a.w*a.w
                + b.x*b.x + b.y*b.y + b.z*b.z + b.w*b.w;
        #pragma unroll
        for (int m = 1; m < 64; m <<= 1){ s += __shfl_xor(s, m, 64); q += __shfl_xor(q, m, 64); }
        float mu  = s * (1.f / 512.f);
        float var = fmaxf(q * (1.f / 512.f) - mu * mu, 0.f);
        float r   = rsqrtf(var + 1e-5f);
        const float* gr = g + lane * 8;
        float4 g0 = *(const float4*)gr;
        float4 g1 = *(const float4*)(gr + 4);
        bf16x8 o;
        o[0] = f2bs((a.x - mu) * r * g0.x); o[1] = f2bs((a.y - mu) * r * g0.y);
        o[2] = f2bs((a.z - mu) * r * g0.z); o[3] = f2bs((a.w - mu) * r * g0.w);
        o[4] = f2bs((b.x - mu) * r * g1.x); o[5] = f2bs((b.y - mu) * r * g1.y);
        o[6] = f2bs((b.z - mu) * r * g1.z); o[7] = f2bs((b.w - mu) * r * g1.w);
        *(bf16x8*)(xnb + row * 512 + lane * 8) = o;
        return;
    }
    int bid = blockIdx.x - 2048;
    if (bid == 144){   // null K/V row (key 0, all batches)
        int b = t >> 6, d = t & 63;
        kb[((size_t)b * KCAP) * 64 + d] = f2bs(nkv[d]);
        vbt[((size_t)b * 64 + d) * KCAP + 0] = f2bs(nkv[64 + d]);
        return;
    }
    if (bid == 145){   // zero K/V pads + build bf16 mask frags (B-operand order)
        int b = t >> 6, i6 = t & 63;
        // kb pad rows 2049..2175 -> 0 (pad S = q.0 = 0, P = 1, finite; excluded by V=0 & mv=0)
        for (int rr = 2049 + i6; rr < KCAP; rr += 64){
            short* kr = kb + ((size_t)b * KCAP + rr) * 64;
            #pragma unroll
            for (int d = 0; d < 64; d += 8) *(int4*)(kr + d) = make_int4(0, 0, 0, 0);
        }
        {   // vbt pad cols 2049..2175 -> 0 (masked-by-zero V)
            short* vr = vbt + ((size_t)b * 64 + i6) * KCAP;
            for (int k = 2049; k < KCAP; k++) vr[k] = 0;
        }
        // mv frag order: lane = s*16 + hb*8 + j; key(s,hb,j) = (s>>1)*32 + 8*g + 4*hb + (j&3)
        int lane = t & 63;
        int s = lane >> 4, hb = (lane >> 3) & 1, j = lane & 7;
        int g = (j < 4) ? ((2 * s) & 3) : ((2 * s + 1) & 3);
        int kl = (s >> 1) * 32 + 8 * g + 4 * hb + (j & 3);
        const int* mrow = mask + b * Nx;
        for (int wi = 0; wi < NTILES; wi++){
            int gk = wi * 64 + kl;    // global key (0 = null key, always valid)
            int ok = (gk == 0) ? 1 : ((gk <= Nx) ? mrow[gk - 1] : 0);
            mvb[(size_t)b * KCAP + wi * 64 + lane] = ok ? (short)0x3F80 : (short)0;
        }
        return;
    }
    // ---- LDS-tiled transpose: 0..79 WcatT (640x512), 80..143 WoutT (512x512) ----
    bool isOut = (bid >= 80);
    int b2 = isOut ? bid - 80 : bid;
    int ntile = isOut ? (b2 & 7) : (b2 % 10);
    int ktile = isOut ? (b2 >> 3) : (b2 / 10);
    int n0 = ntile * 64, k0 = ktile * 64;
    #pragma unroll
    for (int rr = 0; rr < 64; rr += 16){   // coalesced float4 reads of W[k][n]
        int r = rr + (t >> 4), c = (t & 15) * 4;
        float4 v;
        if (isOut)            v = *(const float4*)(Wout + (size_t)(k0 + r) * 512 + n0 + c);
        else if (n0 < 512)    v = *(const float4*)(Wq   + (size_t)(k0 + r) * 512 + n0 + c);
        else                  v = *(const float4*)(Wkv  + (size_t)(k0 + r) * 128 + (n0 - 512) + c);
        ls[c + 0][r] = v.x; ls[c + 1][r] = v.y; ls[c + 2][r] = v.z; ls[c + 3][r] = v.w;
    }
    __syncthreads();
    int rn = t >> 2, kc = (t & 3) * 16;    // coalesced 32B bf16 writes of W^T[n][k]
    short tmp[16];
    #pragma unroll
    for (int j = 0; j < 16; j++) tmp[j] = f2bs(ls[rn][kc + j]);
    short* dst = (isOut ? WoutT : WcatT) + (size_t)(n0 + rn) * 512 + k0 + kc;
    *(int4*)dst       = *(int4*)&tmp[0];
    *(int4*)(dst + 8) = *(int4*)&tmp[8];
}

// ---------------- LN2: fp32 in -> fp32 out, wave per row ----------------
__global__ void __launch_bounds__(256) ln2_kernel(const float* __restrict__ z,
                                                  const float* __restrict__ g,
                                                  float* __restrict__ out){
    int w = threadIdx.x >> 6, lane = threadIdx.x & 63;
    size_t row = (size_t)blockIdx.x * 4 + w;
    const float* xr = z + row * 512 + lane * 8;
    float4 a = *(const float4*)xr;
    float4 b = *(const float4*)(xr + 4);
    float s = a.x + a.y + a.z + a.w + b.x + b.y + b.z + b.w;
    float q = a.x*a.x + a.y*a.y + a.z*a.z + a.w*a.w
            + b.x*b.x + b.y*b.y + b.z*b.z + b.w*b.w;
    #pragma unroll
    for (int m = 1; m < 64; m <<= 1){ s += __shfl_xor(s, m, 64); q += __shfl_xor(q, m, 64); }
    float mu  = s * (1.f / 512.f);
    float var = fmaxf(q * (1.f / 512.f) - mu * mu, 0.f);
    float r   = rsqrtf(var + 1e-5f);
    const float* gr = g + lane * 8;
    float4 g0 = *(const float4*)gr;
    float4 g1 = *(const float4*)(gr + 4);
    float4 o0, o1;
    o0.x = (a.x - mu) * r * g0.x; o0.y = (a.y - mu) * r * g0.y;
    o0.z = (a.z - mu) * r * g0.z; o0.w = (a.w - mu) * r * g0.w;
    o1.x = (b.x - mu) * r * g1.x; o1.y = (b.y - mu) * r * g1.y;
    o1.z = (b.z - mu) * r * g1.z; o1.w = (b.w - mu) * r * g1.w;
    float* op = out + row * 512 + lane * 8;
    *(float4*)op = o0; *(float4*)(op + 4) = o1;
}

// ---------------- GEMM QKV: 128x160 tile, grid (4,64) = 256 blocks ----------------
// C = xn @ [Wq|Wkv] (N=640): q-scale(incl log2e) + K scatter + V^T scatter epilogue (bf16)
// V epilogue applies the key mask (masked keys' V cols = 0) — removes masking from attn.
__global__ void __launch_bounds__(256, 1) gemm_qkv(const short* __restrict__ A,
                                                   const short* __restrict__ BwT,
                                                   const int* __restrict__ mask,
                                                   short* __restrict__ qb,
                                                   short* __restrict__ kb,
                                                   short* __restrict__ vbt){
    __shared__ short As[2][128][72];   // [buf][m][k]
    __shared__ short Bs[2][160][72];   // [buf][n][k]
    int t = threadIdx.x;
    int lane = t & 63, w = t >> 6;
    int l16 = lane & 15, quad = lane >> 4;
    int wm = w & 1, wn = w >> 1;
    int row0 = blockIdx.y * 128, col0 = blockIdx.x * 160;
    f32x4 acc[4][5];
    #pragma unroll
    for (int i = 0; i < 4; i++)
        #pragma unroll
        for (int j = 0; j < 5; j++) acc[i][j] = (f32x4){0.f, 0.f, 0.f, 0.f};
    int ar = t >> 1, ak = (t & 1) * 32;
    const short* ap = A + (size_t)(row0 + ar) * 512 + ak;
    int4 a0 = *(const int4*)(ap);      int4 a1 = *(const int4*)(ap + 8);
    int4 a2 = *(const int4*)(ap + 16); int4 a3 = *(const int4*)(ap + 24);
    // B staging: 160 rows x 64 k = 1280 int4, 5 per thread, coalesced (idx = pass*256 + t)
    int4 pb[5];
    int brow[5], bseg[5];
    #pragma unroll
    for (int ps = 0; ps < 5; ps++){
        int idx = ps * 256 + t;
        brow[ps] = idx >> 3; bseg[ps] = (idx & 7) * 8;
        pb[ps] = *(const int4*)(BwT + (size_t)(col0 + brow[ps]) * 512 + bseg[ps]);
    }
    int p = 0;
    for (int k0 = 0; k0 < 512; k0 += 64){
        *(int4*)&As[p][ar][ak]      = a0;
        *(int4*)&As[p][ar][ak + 8]  = a1;
        *(int4*)&As[p][ar][ak + 16] = a2;
        *(int4*)&As[p][ar][ak + 24] = a3;
        #pragma unroll
        for (int ps = 0; ps < 5; ps++)
            *(int4*)&Bs[p][brow[ps]][bseg[ps]] = pb[ps];
        __syncthreads();
        int kn = k0 + 64;
        if (kn < 512){   // prefetch next k-slab while computing this one
            a0 = *(const int4*)(ap + kn);      a1 = *(const int4*)(ap + kn + 8);
            a2 = *(const int4*)(ap + kn + 16); a3 = *(const int4*)(ap + kn + 24);
            #pragma unroll
            for (int ps = 0; ps < 5; ps++)
                pb[ps] = *(const int4*)(BwT + (size_t)(col0 + brow[ps]) * 512 + kn + bseg[ps]);
        }
        #pragma unroll
        for (int ks = 0; ks < 2; ks++){
            bf16x8 af[4], bfr[5];
            #pragma unroll
            for (int mt = 0; mt < 4; mt++)
                af[mt] = *(const bf16x8*)&As[p][wm * 64 + mt * 16 + l16][ks * 32 + quad * 8];
            #pragma unroll
            for (int nt = 0; nt < 5; nt++)
                bfr[nt] = *(const bf16x8*)&Bs[p][wn * 80 + nt * 16 + l16][ks * 32 + quad * 8];
            #pragma unroll
            for (int mt = 0; mt < 4; mt++)
                #pragma unroll
                for (int nt = 0; nt < 5; nt++)
                    acc[mt][nt] = __builtin_amdgcn_mfma_f32_16x16x32_bf16(af[mt], bfr[nt], acc[mt][nt], 0, 0, 0);
        }
        p ^= 1;
    }
    #pragma unroll
    for (int mt = 0; mt < 4; mt++)
        #pragma unroll
        for (int nt = 0; nt < 5; nt++)
            #pragma unroll
            for (int r = 0; r < 4; r++){
                int row = row0 + wm * 64 + mt * 16 + quad * 4 + r;
                int col = col0 + wn * 80 + nt * 16 + l16;
                float v = acc[mt][nt][r];
                int bb = row >> 11, ii = row & 2047;
                if (col < 512){
                    qb[(size_t)row * 512 + col] = f2bs(v * QSCALE);
                } else if (col < 576){
                    kb[((size_t)bb * KCAP + ii + 1) * 64 + (col - 512)] = f2bs(v);
                } else {
                    if (!mask[bb * Nx + ii]) v = 0.f;   // masked key -> zero V column
                    vbt[((size_t)bb * 64 + (col - 576)) * KCAP + ii + 1] = f2bs(v);
                }
            }
}

// ---------------- GEMM OUT: 128x128 tile, grid (4,64) = 256 blocks, fp32 out ------
__global__ void __launch_bounds__(256, 2) gemm_out(const short* __restrict__ A,
                                                   const short* __restrict__ BwT,
                                                   float* __restrict__ C){
    __shared__ short As[2][128][72];
    __shared__ short Bs[2][128][72];
    int t = threadIdx.x;
    int lane = t & 63, w = t >> 6;
    int l16 = lane & 15, quad = lane >> 4;
    int wm = w & 1, wn = w >> 1;
    int row0 = blockIdx.y * 128, col0 = blockIdx.x * 128;
    f32x4 acc[4][4];
    #pragma unroll
    for (int i = 0; i < 4; i++)
        #pragma unroll
        for (int j = 0; j < 4; j++) acc[i][j] = (f32x4){0.f, 0.f, 0.f, 0.f};
    int ar = t >> 1, ak = (t & 1) * 32;
    const short* ap = A   + (size_t)(row0 + ar) * 512 + ak;
    const short* bp = BwT + (size_t)(col0 + ar) * 512 + ak;
    int4 a0 = *(const int4*)(ap);      int4 a1 = *(const int4*)(ap + 8);
    int4 a2 = *(const int4*)(ap + 16); int4 a3 = *(const int4*)(ap + 24);
    int4 b0 = *(const int4*)(bp);      int4 b1 = *(const int4*)(bp + 8);
    int4 b2 = *(const int4*)(bp + 16); int4 b3 = *(const int4*)(bp + 24);
    int p = 0;
    for (int k0 = 0; k0 < 512; k0 += 64){
        *(int4*)&As[p][ar][ak]      = a0;
        *(int4*)&As[p][ar][ak + 8]  = a1;
        *(int4*)&As[p][ar][ak + 16] = a2;
        *(int4*)&As[p][ar][ak + 24] = a3;
        *(int4*)&Bs[p][ar][ak]      = b0;
        *(int4*)&Bs[p][ar][ak + 8]  = b1;
        *(int4*)&Bs[p][ar][ak + 16] = b2;
        *(int4*)&Bs[p][ar][ak + 24] = b3;
        __syncthreads();
        int kn = k0 + 64;
        if (kn < 512){
            a0 = *(const int4*)(ap + kn);      a1 = *(const int4*)(ap + kn + 8);
            a2 = *(const int4*)(ap + kn + 16); a3 = *(const int4*)(ap + kn + 24);
            b0 = *(const int4*)(bp + kn);      b1 = *(const int4*)(bp + kn + 8);
            b2 = *(const int4*)(bp + kn + 16); b3 = *(const int4*)(bp + kn + 24);
        }
        #pragma unroll
        for (int ks = 0; ks < 2; ks++){
            bf16x8 af[4], bfr[4];
            #pragma unroll
            for (int mt = 0; mt < 4; mt++)
                af[mt] = *(const bf16x8*)&As[p][wm * 64 + mt * 16 + l16][ks * 32 + quad * 8];
            #pragma unroll
            for (int nt = 0; nt < 4; nt++)
                bfr[nt] = *(const bf16x8*)&Bs[p][wn * 64 + nt * 16 + l16][ks * 32 + quad * 8];
            #pragma unroll
            for (int mt = 0; mt < 4; mt++)
                #pragma unroll
                for (int nt = 0; nt < 4; nt++)
                    acc[mt][nt] = __builtin_amdgcn_mfma_f32_16x16x32_bf16(af[mt], bfr[nt], acc[mt][nt], 0, 0, 0);
        }
        p ^= 1;
    }
    #pragma unroll
    for (int mt = 0; mt < 4; mt++)
        #pragma unroll
        for (int nt = 0; nt < 4; nt++)
            #pragma unroll
            for (int r = 0; r < 4; r++){
                int row = row0 + wm * 64 + mt * 16 + quad * 4 + r;
                int col = col0 + wn * 64 + nt * 16 + l16;
                C[(size_t)row * 512 + col] = acc[mt][nt][r];
            }
}

// ---------------- MFMA attention v12: key-split (v11) with corrected launch bounds ----------
// v11's VGPR_Count=64 + 180MB FETCH showed __launch_bounds__(512,4) was treated as 4 BLOCKS/CU
// (32 waves/CU -> 64-VGPR cap -> massive spill). (512,2) caps at >=128 VGPR under either
// interpretation; loop body needs ~80 (v10 measurement) -> no spill, and 73.7KB LDS still
// gives 2 blocks/CU = 16 waves/CU = 4 waves/SIMD (double v10's concurrency).
// Correctness of this structure is HW-verified: v11 (round 9) passed, absmax 0.0234375,
// with the same 512-thread block and same 73728-byte LDS (only regalloc differs here).
__global__ void __launch_bounds__(512, 2) attn_kernel(const short* __restrict__ qb,
                                                      const short* __restrict__ kb,
                                                      const short* __restrict__ vbt,
                                                      const short* __restrict__ mvb,
                                                      short* __restrict__ ob){
    __shared__ short smem[36864];   // 73.7 KB: K = [half][buf][64][72], V = +18432 same layout
    int t = threadIdx.x;
    int lane = t & 63, w = t >> 6;          // w 0..7
    int half = w >> 2, w4 = w & 3;
    int n32 = lane & 31, hb = lane >> 5;
    int b = blockIdx.y, i0 = blockIdx.x * 16;
    int head = 2 * w4 + (n32 >> 4), row = i0 + (n32 & 15);
    // Q frags (B-operand): B[k=8hb+j][n=n32]
    bf16x8 qf[4];
    {
        const short* qp = qb + ((size_t)(b * Nx + row)) * 512 + head * 64 + hb * 8;
        #pragma unroll
        for (int ks = 0; ks < 4; ks++) qf[ks] = *(const bf16x8*)(qp + ks * 16);
    }
    f32x16 oacc[2], lacc;
    #pragma unroll
    for (int j = 0; j < 16; j++){ oacc[0][j] = 0.f; oacc[1][j] = 0.f; lacc[j] = 0.f; }

    int th = t & 255;                        // index within half (4 waves stage one tile)
    int skey = th >> 2, sd = (th & 3) * 16;  // K staging: 64 keys x 64 d
    int vd   = th >> 2, vk = (th & 3) * 16;  // V staging: 64 d x 64 keys
    short* Kb = smem +         (half * 2) * 4608;          // [buf][64][72] per half
    short* Vb = smem + 18432 + (half * 2) * 4608;
    const short* kgp = kb  + (size_t)b * KCAP * 64 + skey * 64 + sd;
    const short* vgp = vbt + ((size_t)b * 64 + vd) * KCAP + vk;
    const short* mvq = mvb + (size_t)b * KCAP + hb * 8;    // mask frags, B-operand order

    // per-block stagger + per-half split: half 0 tiles off..off+16, half 1 off+17..off+33
    int off = (blockIdx.x + 8 * blockIdx.y) % NTILES;
    int jt = off + (half ? 17 : 0); if (jt >= NTILES) jt -= NTILES;

    // prefetch first tile
    int4 pk0 = *(const int4*)(kgp + (size_t)jt * 4096);
    int4 pk1 = *(const int4*)(kgp + (size_t)jt * 4096 + 8);
    int4 pv0 = *(const int4*)(vgp + jt * 64);
    int4 pv1 = *(const int4*)(vgp + jt * 64 + 8);

    int p = 0;
    for (int it = 0; it < 17; ++it){
        short* Ksp = Kb + p * 4608;
        short* Vtp = Vb + p * 4608;
        *(int4*)&Ksp[skey * 72 + sd]     = pk0;
        *(int4*)&Ksp[skey * 72 + sd + 8] = pk1;
        // bit2<->bit3 key permutation == swap middle dwords of the two int4s
        *(int4*)&Vtp[vd * 72 + vk]       = make_int4(pv0.x, pv0.y, pv1.x, pv1.y);
        *(int4*)&Vtp[vd * 72 + vk + 8]   = make_int4(pv0.z, pv0.w, pv1.z, pv1.w);
        __syncthreads();
        // mask frags for THIS tile
        bf16x8 mvf[4];
        #pragma unroll
        for (int s = 0; s < 4; s++) mvf[s] = *(const bf16x8*)(mvq + jt * 64 + s * 16);
        int jn = jt + 1; if (jn == NTILES) jn = 0;   // next tile in rotated order
        // prefetch next tile into regs (hides under compute; last iter's is unused but safe)
        pk0 = *(const int4*)(kgp + (size_t)jn * 4096);
        pk1 = *(const int4*)(kgp + (size_t)jn * 4096 + 8);
        pv0 = *(const int4*)(vgp + jn * 64);
        pv1 = *(const int4*)(vgp + jn * 64 + 8);
        // S^T = K.Q^T from LDS K frags
        f32x16 sf[2];
        #pragma unroll
        for (int i = 0; i < 2; i++)
            #pragma unroll
            for (int j = 0; j < 16; j++) sf[i][j] = 0.f;
        __builtin_amdgcn_s_setprio(1);
        #pragma unroll
        for (int ks = 0; ks < 4; ks++){
            #pragma unroll
            for (int kt = 0; kt < 2; kt++){
                bf16x8 kf = *(const bf16x8*)&Ksp[(kt * 32 + n32) * 72 + ks * 16 + hb * 8];
                sf[kt] = __builtin_amdgcn_mfma_f32_32x32x16_bf16(kf, qf[ks], sf[kt], 0, 0, 0);
            }
        }
        __builtin_amdgcn_s_setprio(0);
        // exp2 + truncating pack — NO masking (handled by zeroed V + maskvec L)
        unsigned pg[8][2];
        #pragma unroll
        for (int kt = 0; kt < 2; kt++){
            #pragma unroll
            for (int g4 = 0; g4 < 4; g4++){
                float pr[4];
                #pragma unroll
                for (int tt = 0; tt < 4; tt++)
                    pr[tt] = __builtin_amdgcn_exp2f(sf[kt][g4 * 4 + tt]);
                pg[kt * 4 + g4][0] = pack_trunc(pr[0], pr[1]);
                pg[kt * 4 + g4][1] = pack_trunc(pr[2], pr[3]);
            }
        }
        // PV + masked L: pa lane-local (V pre-permuted); lacc rows align with oacc rows
        __builtin_amdgcn_s_setprio(1);
        #pragma unroll
        for (int s = 0; s < 4; s++){
            bf16x8 pa = __builtin_bit_cast(bf16x8,
                (u32x4){pg[2 * s][0], pg[2 * s][1], pg[2 * s + 1][0], pg[2 * s + 1][1]});
            lacc = __builtin_amdgcn_mfma_f32_32x32x16_bf16(pa, mvf[s], lacc, 0, 0, 0);
            #pragma unroll
            for (int nt = 0; nt < 2; nt++){
                bf16x8 vf = *(const bf16x8*)&Vtp[(nt * 32 + n32) * 72 + s * 16 + hb * 8];
                oacc[nt] = __builtin_amdgcn_mfma_f32_32x32x16_bf16(pa, vf, oacc[nt], 0, 0, 0);
            }
        }
        __builtin_amdgcn_s_setprio(0);
        p ^= 1;
        jt = jn;
    }
    // ---- combine halves: half 1 -> LDS (stride 49 to dodge bank conflicts), half 0 sums ----
    __syncthreads();                       // all compute done; staging buffers now dead
    float* cm = (float*)smem;              // 18432 floats available; need 256*49 = 12544
    int base = (w4 * 64 + lane) * 49;
    if (half){
        #pragma unroll
        for (int r = 0; r < 16; r++){
            cm[base + r]      = lacc[r];
            cm[base + 16 + r] = oacc[0][r];
            cm[base + 32 + r] = oacc[1][r];
        }
    }
    __syncthreads();
    if (!half){
        #pragma unroll
        for (int r = 0; r < 16; r++){
            lacc[r]    += cm[base + r];
            oacc[0][r] += cm[base + 16 + r];
            oacc[1][r] += cm[base + 32 + r];
        }
        // normalize + store: reg r of lacc holds L for the same (head,row) as reg r of oacc
        #pragma unroll
        for (int r = 0; r < 16; r++){
            float linv = 1.f / lacc[r];
            int hr = (r & 3) + 8 * (r >> 2) + 4 * hb;
            int grow = i0 + (hr & 15);
            int ghead = 2 * w4 + (hr >> 4);
            short* op = ob + ((size_t)(b * Nx + grow)) * 512 + ghead * 64 + n32;
            op[0]  = f2bs(oacc[0][r] * linv);
            op[32] = f2bs(oacc[1][r] * linv);
        }
    }
}

extern "C" void kernel_launch(void* const* d_in, const int* in_sizes, int n_in,
                              void* d_out, int out_size, void* d_ws, size_t ws_size,
                              hipStream_t stream){
    const float* x     = (const float*)d_in[0];
    const int*   mask  = (const int*)  d_in[1];
    const float* gamma = (const float*)d_in[2];
    const float* Wq    = (const float*)d_in[3];
    const float* Wkv   = (const float*)d_in[4];
    const float* nkv   = (const float*)d_in[5];
    const float* Wout  = (const float*)d_in[6];
    const float* og    = (const float*)d_in[7];
    float* out = (float*)d_out;

    short* xnb   = (short*)d_ws;                 // 4194304 shorts
    short* qb    = xnb + (size_t)4194304;        // 4194304
    short* kb    = qb  + (size_t)4194304;        // 4*KCAP*64 = 557056 (pads zeroed)
    short* vbt   = kb  + (size_t)557056;         // 557056 (pads zeroed)
    short* ob    = vbt + (size_t)557056;         // 4194304
    short* WcatT = ob  + (size_t)4194304;        // 327680
    short* WoutT = WcatT + (size_t)327680;       // 262144
    short* mvb   = WoutT + (size_t)262144;       // 4*KCAP = 8704 (bf16 mask frags)
    float* zb    = (float*)d_ws;                 // aliases xnb+qb (both dead by gemm_out)

    ln1_prep_kernel<<<2194, 256, 0, stream>>>(x, gamma, xnb, Wq, Wkv, Wout, nkv, mask,
                                              WcatT, WoutT, kb, vbt, mvb);
    gemm_qkv    <<<dim3(4, 64), 256, 0, stream>>>(xnb, WcatT, mask, qb, kb, vbt);
    attn_kernel <<<dim3(128, 4), 512, 0, stream>>>(qb, kb, vbt, mvb, ob);
    gemm_out    <<<dim3(4, 64), 256, 0, stream>>>(ob, WoutT, zb);
    ln2_kernel  <<<2048, 256, 0, stream>>>(zb, og, out);
}

// Round 16
// 202.765 us; speedup vs baseline: 1.1786x; 1.0708x over previous
//
#include <hip/hip_runtime.h>

typedef __attribute__((ext_vector_type(8)))  short bf16x8;   // MFMA A/B frag (4 VGPRs)
typedef __attribute__((ext_vector_type(4)))  float f32x4;    // 16x16 C/D frag
typedef __attribute__((ext_vector_type(16))) float f32x16;   // 32x32 C/D frag
typedef __attribute__((ext_vector_type(4)))  unsigned u32x4;

#define Nx 2048
#define CTXx 2049
#define KCAP 2112          // 2049 real keys + pad; pad K rows/V cols ZEROED (P=1 x V=0 = 0)
#define QSCALE 0.18033688f // 0.125 * log2(e): softmax computed as 2^(S*log2e) = e^S

__device__ __forceinline__ short f2bs(float x){   // float -> bf16 bits (RNE)
    unsigned u = __builtin_bit_cast(unsigned, x);
    u = (u + 0x7fffu + ((u >> 16) & 1u)) >> 16;
    return (short)u;
}
// truncating pack: (hi16 of b)<<16 | (hi16 of a) — 1 v_perm_b32
__device__ __forceinline__ unsigned pack_trunc(float a, float b){
    return __builtin_amdgcn_perm(__builtin_bit_cast(unsigned, b),
                                 __builtin_bit_cast(unsigned, a), 0x07060302u);
}

// ---------------- fused LN1 (blocks 0..2047) + weight prep (2048..2193) ----------------
__global__ void __launch_bounds__(256) ln1_prep_kernel(const float* __restrict__ x,
                                                       const float* __restrict__ g,
                                                       short* __restrict__ xnb,
                                                       const float* __restrict__ Wq,
                                                       const float* __restrict__ Wkv,
                                                       const float* __restrict__ Wout,
                                                       const float* __restrict__ nkv,
                                                       const int* __restrict__ mask,
                                                       short* __restrict__ WcatT,
                                                       short* __restrict__ WoutT,
                                                       short* __restrict__ kb,
                                                       short* __restrict__ vbt,
                                                       short* __restrict__ mvb){
    __shared__ float ls[64][65];
    int t = threadIdx.x;
    if (blockIdx.x < 2048){    // ---- LN1: wave per row, fp32 -> bf16 ----
        int w = t >> 6, lane = t & 63;
        size_t row = (size_t)blockIdx.x * 4 + w;
        const float* xr = x + row * 512 + lane * 8;
        float4 a = *(const float4*)xr;
        float4 b = *(const float4*)(xr + 4);
        float s = a.x + a.y + a.z + a.w + b.x + b.y + b.z + b.w;
        float q = a.x*a.x + a.y*a.y + a.z*a.z + a.w*a.w
                + b.x*b.x + b.y*b.y + b.z*b.z + b.w*b.w;
        #pragma unroll
        for (int m = 1; m < 64; m <<= 1){ s += __shfl_xor(s, m, 64); q += __shfl_xor(q, m, 64); }
        float mu  = s * (1.f / 512.f);
        float var = fmaxf(q * (1.f / 512.f) - mu * mu, 0.f);
        float r   = rsqrtf(var + 1e-5f);
        const float* gr = g + lane * 8;
        float4 g0 = *(const float4*)gr;
        float4 g1 = *(const float4*)(gr + 4);
        bf16x8 o;
        o[0] = f2bs((a.x - mu) * r * g0.x); o[1] = f2bs((a.y - mu) * r * g0.y);
        o[2] = f2bs((a.z - mu) * r * g0.z); o[3] = f2bs((a.w - mu) * r * g0.w);
        o[4] = f2bs((b.x - mu) * r * g1.x); o[5] = f2bs((b.y - mu) * r * g1.y);
        o[6] = f2bs((b.z - mu) * r * g1.z); o[7] = f2bs((b.w - mu) * r * g1.w);
        *(bf16x8*)(xnb + row * 512 + lane * 8) = o;
        return;
    }
    int bid = blockIdx.x - 2048;
    if (bid == 144){   // null K/V row (key 0, all batches)
        int b = t >> 6, d = t & 63;
        kb[((size_t)b * KCAP) * 64 + d] = f2bs(nkv[d]);
        vbt[((size_t)b * 64 + d) * KCAP + 0] = f2bs(nkv[64 + d]);
        return;
    }
    if (bid == 145){   // zero K/V pads + build bf16 mask frags (B-operand order)
        int b = t >> 6, i6 = t & 63;
        if (i6 < 63){   // kb pad rows 2049..2111 -> 0 (so pad S = q.0 = 0, P = 1, finite)
            short* kr = kb + ((size_t)b * KCAP + 2049 + i6) * 64;
            #pragma unroll
            for (int d = 0; d < 64; d += 8) *(int4*)(kr + d) = make_int4(0, 0, 0, 0);
        }
        {   // vbt pad cols 2049..2111 -> 0 (masked-by-zero V)
            short* vr = vbt + ((size_t)b * 64 + i6) * KCAP;
            for (int k = 2049; k < KCAP; k++) vr[k] = 0;
        }
        // mv frag order: lane = s*16 + hb*8 + j; key(s,hb,j) = (s>>1)*32 + 8*g + 4*hb + (j&3)
        int lane = t & 63;
        int s = lane >> 4, hb = (lane >> 3) & 1, j = lane & 7;
        int g = (j < 4) ? ((2 * s) & 3) : ((2 * s + 1) & 3);
        int kl = (s >> 1) * 32 + 8 * g + 4 * hb + (j & 3);
        const int* mrow = mask + b * Nx;
        for (int wi = 0; wi < 33; wi++){
            int gk = wi * 64 + kl;    // global key (0 = null key, always valid)
            int ok = (gk == 0) ? 1 : ((gk <= Nx) ? mrow[gk - 1] : 0);
            mvb[(size_t)b * 2112 + wi * 64 + lane] = ok ? (short)0x3F80 : (short)0;
        }
        return;
    }
    // ---- LDS-tiled transpose: 0..79 WcatT (640x512), 80..143 WoutT (512x512) ----
    bool isOut = (bid >= 80);
    int b2 = isOut ? bid - 80 : bid;
    int ntile = isOut ? (b2 & 7) : (b2 % 10);
    int ktile = isOut ? (b2 >> 3) : (b2 / 10);
    int n0 = ntile * 64, k0 = ktile * 64;
    #pragma unroll
    for (int rr = 0; rr < 64; rr += 16){   // coalesced float4 reads of W[k][n]
        int r = rr + (t >> 4), c = (t & 15) * 4;
        float4 v;
        if (isOut)            v = *(const float4*)(Wout + (size_t)(k0 + r) * 512 + n0 + c);
        else if (n0 < 512)    v = *(const float4*)(Wq   + (size_t)(k0 + r) * 512 + n0 + c);
        else                  v = *(const float4*)(Wkv  + (size_t)(k0 + r) * 128 + (n0 - 512) + c);
        ls[c + 0][r] = v.x; ls[c + 1][r] = v.y; ls[c + 2][r] = v.z; ls[c + 3][r] = v.w;
    }
    __syncthreads();
    int rn = t >> 2, kc = (t & 3) * 16;    // coalesced 32B bf16 writes of W^T[n][k]
    short tmp[16];
    #pragma unroll
    for (int j = 0; j < 16; j++) tmp[j] = f2bs(ls[rn][kc + j]);
    short* dst = (isOut ? WoutT : WcatT) + (size_t)(n0 + rn) * 512 + k0 + kc;
    *(int4*)dst       = *(int4*)&tmp[0];
    *(int4*)(dst + 8) = *(int4*)&tmp[8];
}

// ---------------- LN2: fp32 in -> fp32 out, wave per row ----------------
__global__ void __launch_bounds__(256) ln2_kernel(const float* __restrict__ z,
                                                  const float* __restrict__ g,
                                                  float* __restrict__ out){
    int w = threadIdx.x >> 6, lane = threadIdx.x & 63;
    size_t row = (size_t)blockIdx.x * 4 + w;
    const float* xr = z + row * 512 + lane * 8;
    float4 a = *(const float4*)xr;
    float4 b = *(const float4*)(xr + 4);
    float s = a.x + a.y + a.z + a.w + b.x + b.y + b.z + b.w;
    float q = a.x*a.x + a.y*a.y + a.z*a.z + a.w*a.w
            + b.x*b.x + b.y*b.y + b.z*b.z + b.w*b.w;
    #pragma unroll
    for (int m = 1; m < 64; m <<= 1){ s += __shfl_xor(s, m, 64); q += __shfl_xor(q, m, 64); }
    float mu  = s * (1.f / 512.f);
    float var = fmaxf(q * (1.f / 512.f) - mu * mu, 0.f);
    float r   = rsqrtf(var + 1e-5f);
    const float* gr = g + lane * 8;
    float4 g0 = *(const float4*)gr;
    float4 g1 = *(const float4*)(gr + 4);
    float4 o0, o1;
    o0.x = (a.x - mu) * r * g0.x; o0.y = (a.y - mu) * r * g0.y;
    o0.z = (a.z - mu) * r * g0.z; o0.w = (a.w - mu) * r * g0.w;
    o1.x = (b.x - mu) * r * g1.x; o1.y = (b.y - mu) * r * g1.y;
    o1.z = (b.z - mu) * r * g1.z; o1.w = (b.w - mu) * r * g1.w;
    float* op = out + row * 512 + lane * 8;
    *(float4*)op = o0; *(float4*)(op + 4) = o1;
}

// ---------------- GEMM QKV: 128x160 tile, grid (4,64) = 256 blocks ----------------
// C = xn @ [Wq|Wkv] (N=640): q-scale(incl log2e) + K scatter + V^T scatter epilogue (bf16)
// V epilogue applies the key mask (masked keys' V cols = 0) — removes masking from attn.
__global__ void __launch_bounds__(256, 1) gemm_qkv(const short* __restrict__ A,
                                                   const short* __restrict__ BwT,
                                                   const int* __restrict__ mask,
                                                   short* __restrict__ qb,
                                                   short* __restrict__ kb,
                                                   short* __restrict__ vbt){
    __shared__ short As[2][128][72];   // [buf][m][k]
    __shared__ short Bs[2][160][72];   // [buf][n][k]
    int t = threadIdx.x;
    int lane = t & 63, w = t >> 6;
    int l16 = lane & 15, quad = lane >> 4;
    int wm = w & 1, wn = w >> 1;
    int row0 = blockIdx.y * 128, col0 = blockIdx.x * 160;
    f32x4 acc[4][5];
    #pragma unroll
    for (int i = 0; i < 4; i++)
        #pragma unroll
        for (int j = 0; j < 5; j++) acc[i][j] = (f32x4){0.f, 0.f, 0.f, 0.f};
    int ar = t >> 1, ak = (t & 1) * 32;
    const short* ap = A + (size_t)(row0 + ar) * 512 + ak;
    int4 a0 = *(const int4*)(ap);      int4 a1 = *(const int4*)(ap + 8);
    int4 a2 = *(const int4*)(ap + 16); int4 a3 = *(const int4*)(ap + 24);
    // B staging: 160 rows x 64 k = 1280 int4, 5 per thread, coalesced (idx = pass*256 + t)
    int4 pb[5];
    int brow[5], bseg[5];
    #pragma unroll
    for (int ps = 0; ps < 5; ps++){
        int idx = ps * 256 + t;
        brow[ps] = idx >> 3; bseg[ps] = (idx & 7) * 8;
        pb[ps] = *(const int4*)(BwT + (size_t)(col0 + brow[ps]) * 512 + bseg[ps]);
    }
    int p = 0;
    for (int k0 = 0; k0 < 512; k0 += 64){
        *(int4*)&As[p][ar][ak]      = a0;
        *(int4*)&As[p][ar][ak + 8]  = a1;
        *(int4*)&As[p][ar][ak + 16] = a2;
        *(int4*)&As[p][ar][ak + 24] = a3;
        #pragma unroll
        for (int ps = 0; ps < 5; ps++)
            *(int4*)&Bs[p][brow[ps]][bseg[ps]] = pb[ps];
        __syncthreads();
        int kn = k0 + 64;
        if (kn < 512){   // prefetch next k-slab while computing this one
            a0 = *(const int4*)(ap + kn);      a1 = *(const int4*)(ap + kn + 8);
            a2 = *(const int4*)(ap + kn + 16); a3 = *(const int4*)(ap + kn + 24);
            #pragma unroll
            for (int ps = 0; ps < 5; ps++)
                pb[ps] = *(const int4*)(BwT + (size_t)(col0 + brow[ps]) * 512 + kn + bseg[ps]);
        }
        #pragma unroll
        for (int ks = 0; ks < 2; ks++){
            bf16x8 af[4], bfr[5];
            #pragma unroll
            for (int mt = 0; mt < 4; mt++)
                af[mt] = *(const bf16x8*)&As[p][wm * 64 + mt * 16 + l16][ks * 32 + quad * 8];
            #pragma unroll
            for (int nt = 0; nt < 5; nt++)
                bfr[nt] = *(const bf16x8*)&Bs[p][wn * 80 + nt * 16 + l16][ks * 32 + quad * 8];
            #pragma unroll
            for (int mt = 0; mt < 4; mt++)
                #pragma unroll
                for (int nt = 0; nt < 5; nt++)
                    acc[mt][nt] = __builtin_amdgcn_mfma_f32_16x16x32_bf16(af[mt], bfr[nt], acc[mt][nt], 0, 0, 0);
        }
        p ^= 1;
    }
    #pragma unroll
    for (int mt = 0; mt < 4; mt++)
        #pragma unroll
        for (int nt = 0; nt < 5; nt++)
            #pragma unroll
            for (int r = 0; r < 4; r++){
                int row = row0 + wm * 64 + mt * 16 + quad * 4 + r;
                int col = col0 + wn * 80 + nt * 16 + l16;
                float v = acc[mt][nt][r];
                int bb = row >> 11, ii = row & 2047;
                if (col < 512){
                    qb[(size_t)row * 512 + col] = f2bs(v * QSCALE);
                } else if (col < 576){
                    kb[((size_t)bb * KCAP + ii + 1) * 64 + (col - 512)] = f2bs(v);
                } else {
                    if (!mask[bb * Nx + ii]) v = 0.f;   // masked key -> zero V column
                    vbt[((size_t)bb * 64 + (col - 576)) * KCAP + ii + 1] = f2bs(v);
                }
            }
}

// ---------------- GEMM OUT: 128x128 tile, grid (4,64) = 256 blocks, fp32 out ------
__global__ void __launch_bounds__(256, 2) gemm_out(const short* __restrict__ A,
                                                   const short* __restrict__ BwT,
                                                   float* __restrict__ C){
    __shared__ short As[2][128][72];
    __shared__ short Bs[2][128][72];
    int t = threadIdx.x;
    int lane = t & 63, w = t >> 6;
    int l16 = lane & 15, quad = lane >> 4;
    int wm = w & 1, wn = w >> 1;
    int row0 = blockIdx.y * 128, col0 = blockIdx.x * 128;
    f32x4 acc[4][4];
    #pragma unroll
    for (int i = 0; i < 4; i++)
        #pragma unroll
        for (int j = 0; j < 4; j++) acc[i][j] = (f32x4){0.f, 0.f, 0.f, 0.f};
    int ar = t >> 1, ak = (t & 1) * 32;
    const short* ap = A   + (size_t)(row0 + ar) * 512 + ak;
    const short* bp = BwT + (size_t)(col0 + ar) * 512 + ak;
    int4 a0 = *(const int4*)(ap);      int4 a1 = *(const int4*)(ap + 8);
    int4 a2 = *(const int4*)(ap + 16); int4 a3 = *(const int4*)(ap + 24);
    int4 b0 = *(const int4*)(bp);      int4 b1 = *(const int4*)(bp + 8);
    int4 b2 = *(const int4*)(bp + 16); int4 b3 = *(const int4*)(bp + 24);
    int p = 0;
    for (int k0 = 0; k0 < 512; k0 += 64){
        *(int4*)&As[p][ar][ak]      = a0;
        *(int4*)&As[p][ar][ak + 8]  = a1;
        *(int4*)&As[p][ar][ak + 16] = a2;
        *(int4*)&As[p][ar][ak + 24] = a3;
        *(int4*)&Bs[p][ar][ak]      = b0;
        *(int4*)&Bs[p][ar][ak + 8]  = b1;
        *(int4*)&Bs[p][ar][ak + 16] = b2;
        *(int4*)&Bs[p][ar][ak + 24] = b3;
        __syncthreads();
        int kn = k0 + 64;
        if (kn < 512){
            a0 = *(const int4*)(ap + kn);      a1 = *(const int4*)(ap + kn + 8);
            a2 = *(const int4*)(ap + kn + 16); a3 = *(const int4*)(ap + kn + 24);
            b0 = *(const int4*)(bp + kn);      b1 = *(const int4*)(bp + kn + 8);
            b2 = *(const int4*)(bp + kn + 16); b3 = *(const int4*)(bp + kn + 24);
        }
        #pragma unroll
        for (int ks = 0; ks < 2; ks++){
            bf16x8 af[4], bfr[4];
            #pragma unroll
            for (int mt = 0; mt < 4; mt++)
                af[mt] = *(const bf16x8*)&As[p][wm * 64 + mt * 16 + l16][ks * 32 + quad * 8];
            #pragma unroll
            for (int nt = 0; nt < 4; nt++)
                bfr[nt] = *(const bf16x8*)&Bs[p][wn * 64 + nt * 16 + l16][ks * 32 + quad * 8];
            #pragma unroll
            for (int mt = 0; mt < 4; mt++)
                #pragma unroll
                for (int nt = 0; nt < 4; nt++)
                    acc[mt][nt] = __builtin_amdgcn_mfma_f32_16x16x32_bf16(af[mt], bfr[nt], acc[mt][nt], 0, 0, 0);
        }
        p ^= 1;
    }
    #pragma unroll
    for (int mt = 0; mt < 4; mt++)
        #pragma unroll
        for (int nt = 0; nt < 4; nt++)
            #pragma unroll
            for (int r = 0; r < 4; r++){
                int row = row0 + wm * 64 + mt * 16 + quad * 4 + r;
                int col = col0 + wn * 64 + nt * 16 + l16;
                C[(size_t)row * 512 + col] = acc[mt][nt][r];
            }
}

// ---------------- MFMA attention v10 (VERIFIED BEST: 48.8 us): mask-free loop + rotation ----
// Grid (128 row-tiles, 4 batches). Block = 16 q-rows x 8 heads; wave = 2 heads. KVBLK=64.
// Softmax = plain sum of exp (no running max) -> tile order is commutative. Each block starts
// at tile off = (bx + 8*by) % 33 so co-resident blocks are phase-STAGGERED: one block's MFMA
// burst (QK/PV) overlaps the other's VALU burst (exp2/pack) on the shared SIMDs (+8% meas.).
// Masking is out of the loop (zeroed V cols + maskvec L). Key-split variants (v11/v12)
// measured WORSE (57-90 us): 8-wave barrier straggling ate the occupancy gain.
__global__ void __launch_bounds__(256, 2) attn_kernel(const short* __restrict__ qb,
                                                      const short* __restrict__ kb,
                                                      const short* __restrict__ vbt,
                                                      const short* __restrict__ mvb,
                                                      short* __restrict__ ob){
    __shared__ short Ks[2][64][72];   // [buf][key][d]
    __shared__ short Vt[2][64][72];   // [buf][d][key], key cols bit2<->bit3 swapped
    int t = threadIdx.x;
    int lane = t & 63, w = t >> 6;
    int n32 = lane & 31, hb = lane >> 5;
    int b = blockIdx.y, i0 = blockIdx.x * 16;
    int head = 2 * w + (n32 >> 4), row = i0 + (n32 & 15);
    // Q frags (B-operand): B[k=8hb+j][n=n32]
    bf16x8 qf[4];
    {
        const short* qp = qb + ((size_t)(b * Nx + row)) * 512 + head * 64 + hb * 8;
        #pragma unroll
        for (int ks = 0; ks < 4; ks++) qf[ks] = *(const bf16x8*)(qp + ks * 16);
    }
    f32x16 oacc[2], lacc;
    #pragma unroll
    for (int j = 0; j < 16; j++){ oacc[0][j] = 0.f; oacc[1][j] = 0.f; lacc[j] = 0.f; }

    int skey = t >> 2, sd = (t & 3) * 16;   // K staging: 64 keys x 64 d
    int vd   = t >> 2, vk = (t & 3) * 16;   // V staging: 64 d x 64 keys
    const short* kgp = kb  + (size_t)b * KCAP * 64 + skey * 64 + sd;
    const short* vgp = vbt + ((size_t)b * 64 + vd) * KCAP + vk;
    const short* mvq = mvb + (size_t)b * 2112 + hb * 8;   // mask frags, B-operand order

    // phase-stagger: this block's tile visit order is off, off+1, ..., wrapping mod 33
    int off = (blockIdx.x + 8 * blockIdx.y) % 33;

    // prefetch first tile (index off)
    int jt = off;
    int4 pk0 = *(const int4*)(kgp + (size_t)jt * 4096);
    int4 pk1 = *(const int4*)(kgp + (size_t)jt * 4096 + 8);
    int4 pv0 = *(const int4*)(vgp + jt * 64);
    int4 pv1 = *(const int4*)(vgp + jt * 64 + 8);

    int p = 0;
    for (int it = 0; it < 33; ++it){
        *(int4*)&Ks[p][skey][sd]     = pk0;
        *(int4*)&Ks[p][skey][sd + 8] = pk1;
        // bit2<->bit3 key permutation == swap middle dwords of the two int4s
        *(int4*)&Vt[p][vd][vk]       = make_int4(pv0.x, pv0.y, pv1.x, pv1.y);
        *(int4*)&Vt[p][vd][vk + 8]   = make_int4(pv0.z, pv0.w, pv1.z, pv1.w);
        __syncthreads();
        // mask frags for THIS tile
        bf16x8 mvf[4];
        #pragma unroll
        for (int s = 0; s < 4; s++) mvf[s] = *(const bf16x8*)(mvq + jt * 64 + s * 16);
        int jn = jt + 1; if (jn == 33) jn = 0;   // next tile in rotated order
        if (it + 1 < 33){   // prefetch next tile into regs (hides under compute)
            pk0 = *(const int4*)(kgp + (size_t)jn * 4096);
            pk1 = *(const int4*)(kgp + (size_t)jn * 4096 + 8);
            pv0 = *(const int4*)(vgp + jn * 64);
            pv1 = *(const int4*)(vgp + jn * 64 + 8);
        }
        // S^T = K.Q^T from LDS K frags
        f32x16 sf[2];
        #pragma unroll
        for (int i = 0; i < 2; i++)
            #pragma unroll
            for (int j = 0; j < 16; j++) sf[i][j] = 0.f;
        __builtin_amdgcn_s_setprio(1);
        #pragma unroll
        for (int ks = 0; ks < 4; ks++){
            #pragma unroll
            for (int kt = 0; kt < 2; kt++){
                bf16x8 kf = *(const bf16x8*)&Ks[p][kt * 32 + n32][ks * 16 + hb * 8];
                sf[kt] = __builtin_amdgcn_mfma_f32_32x32x16_bf16(kf, qf[ks], sf[kt], 0, 0, 0);
            }
        }
        __builtin_amdgcn_s_setprio(0);
        // exp2 + truncating pack — NO masking (handled by zeroed V + maskvec L)
        unsigned pg[8][2];
        #pragma unroll
        for (int kt = 0; kt < 2; kt++){
            #pragma unroll
            for (int g4 = 0; g4 < 4; g4++){
                float pr[4];
                #pragma unroll
                for (int tt = 0; tt < 4; tt++)
                    pr[tt] = __builtin_amdgcn_exp2f(sf[kt][g4 * 4 + tt]);
                pg[kt * 4 + g4][0] = pack_trunc(pr[0], pr[1]);
                pg[kt * 4 + g4][1] = pack_trunc(pr[2], pr[3]);
            }
        }
        // PV + masked L: pa lane-local (V pre-permuted); lacc rows align with oacc rows
        __builtin_amdgcn_s_setprio(1);
        #pragma unroll
        for (int s = 0; s < 4; s++){
            bf16x8 pa = __builtin_bit_cast(bf16x8,
                (u32x4){pg[2 * s][0], pg[2 * s][1], pg[2 * s + 1][0], pg[2 * s + 1][1]});
            lacc = __builtin_amdgcn_mfma_f32_32x32x16_bf16(pa, mvf[s], lacc, 0, 0, 0);
            #pragma unroll
            for (int nt = 0; nt < 2; nt++){
                bf16x8 vf = *(const bf16x8*)&Vt[p][nt * 32 + n32][s * 16 + hb * 8];
                oacc[nt] = __builtin_amdgcn_mfma_f32_32x32x16_bf16(pa, vf, oacc[nt], 0, 0, 0);
            }
        }
        __builtin_amdgcn_s_setprio(0);
        p ^= 1;
        jt = jn;
    }
    // normalize + store: reg r of lacc holds L for the same (head,row) as reg r of oacc
    #pragma unroll
    for (int r = 0; r < 16; r++){
        float linv = 1.f / lacc[r];
        int hr = (r & 3) + 8 * (r >> 2) + 4 * hb;
        int grow = i0 + (hr & 15);
        int ghead = 2 * w + (hr >> 4);
        short* op = ob + ((size_t)(b * Nx + grow)) * 512 + ghead * 64 + n32;
        op[0]  = f2bs(oacc[0][r] * linv);
        op[32] = f2bs(oacc[1][r] * linv);
    }
}

extern "C" void kernel_launch(void* const* d_in, const int* in_sizes, int n_in,
                              void* d_out, int out_size, void* d_ws, size_t ws_size,
                              hipStream_t stream){
    const float* x     = (const float*)d_in[0];
    const int*   mask  = (const int*)  d_in[1];
    const float* gamma = (const float*)d_in[2];
    const float* Wq    = (const float*)d_in[3];
    const float* Wkv   = (const float*)d_in[4];
    const float* nkv   = (const float*)d_in[5];
    const float* Wout  = (const float*)d_in[6];
    const float* og    = (const float*)d_in[7];
    float* out = (float*)d_out;

    short* xnb   = (short*)d_ws;                 // 4194304 shorts
    short* qb    = xnb + (size_t)4194304;        // 4194304
    short* kb    = qb  + (size_t)4194304;        // 4*KCAP*64 = 540672 (pads zeroed)
    short* vbt   = kb  + (size_t)540672;         // 540672 (pads zeroed)
    short* ob    = vbt + (size_t)540672;         // 4194304
    short* WcatT = ob  + (size_t)4194304;        // 327680
    short* WoutT = WcatT + (size_t)327680;       // 262144
    short* mvb   = WoutT + (size_t)262144;       // 4*33*64 = 8448 (bf16 mask frags)
    float* zb    = (float*)d_ws;                 // aliases xnb+qb (both dead by gemm_out)

    ln1_prep_kernel<<<2194, 256, 0, stream>>>(x, gamma, xnb, Wq, Wkv, Wout, nkv, mask,
                                              WcatT, WoutT, kb, vbt, mvb);
    gemm_qkv    <<<dim3(4, 64), 256, 0, stream>>>(xnb, WcatT, mask, qb, kb, vbt);
    attn_kernel <<<dim3(128, 4), 256, 0, stream>>>(qb, kb, vbt, mvb, ob);
    gemm_out    <<<dim3(4, 64), 256, 0, stream>>>(ob, WoutT, zb);
    ln2_kernel  <<<2048, 256, 0, stream>>>(zb, og, out);
}

// Round 19
// 192.308 us; speedup vs baseline: 1.2427x; 1.0544x over previous
//
#include <hip/hip_runtime.h>

typedef __attribute__((ext_vector_type(8)))  short bf16x8;   // MFMA A/B frag (4 VGPRs)
typedef __attribute__((ext_vector_type(4)))  float f32x4;    // 16x16 C/D frag
typedef __attribute__((ext_vector_type(16))) float f32x16;   // 32x32 C/D frag
typedef __attribute__((ext_vector_type(4)))  unsigned u32x4;

#define Nx 2048
#define CTXx 2049
#define KCAP 2112          // 2049 real keys + pad; pad K rows/V cols ZEROED (P=1 x V=0 = 0)
#define QSCALE 0.18033688f // 0.125 * log2(e): softmax computed as 2^(S*log2e) = e^S

__device__ __forceinline__ short f2bs(float x){   // float -> bf16 bits (RNE)
    unsigned u = __builtin_bit_cast(unsigned, x);
    u = (u + 0x7fffu + ((u >> 16) & 1u)) >> 16;
    return (short)u;
}
// truncating pack: (hi16 of b)<<16 | (hi16 of a) — 1 v_perm_b32
__device__ __forceinline__ unsigned pack_trunc(float a, float b){
    return __builtin_amdgcn_perm(__builtin_bit_cast(unsigned, b),
                                 __builtin_bit_cast(unsigned, a), 0x07060302u);
}

// ---------------- fused LN1 (blocks 0..2047) + weight prep (2048..2193) ----------------
__global__ void __launch_bounds__(256) ln1_prep_kernel(const float* __restrict__ x,
                                                       const float* __restrict__ g,
                                                       short* __restrict__ xnb,
                                                       const float* __restrict__ Wq,
                                                       const float* __restrict__ Wkv,
                                                       const float* __restrict__ Wout,
                                                       const float* __restrict__ nkv,
                                                       const int* __restrict__ mask,
                                                       short* __restrict__ WcatT,
                                                       short* __restrict__ WoutT,
                                                       short* __restrict__ kb,
                                                       short* __restrict__ vbt,
                                                       short* __restrict__ mvb){
    __shared__ float ls[64][65];
    int t = threadIdx.x;
    if (blockIdx.x < 2048){    // ---- LN1: wave per row, fp32 -> bf16 ----
        int w = t >> 6, lane = t & 63;
        size_t row = (size_t)blockIdx.x * 4 + w;
        const float* xr = x + row * 512 + lane * 8;
        float4 a = *(const float4*)xr;
        float4 b = *(const float4*)(xr + 4);
        float s = a.x + a.y + a.z + a.w + b.x + b.y + b.z + b.w;
        float q = a.x*a.x + a.y*a.y + a.z*a.z + a.w*a.w
                + b.x*b.x + b.y*b.y + b.z*b.z + b.w*b.w;
        #pragma unroll
        for (int m = 1; m < 64; m <<= 1){ s += __shfl_xor(s, m, 64); q += __shfl_xor(q, m, 64); }
        float mu  = s * (1.f / 512.f);
        float var = fmaxf(q * (1.f / 512.f) - mu * mu, 0.f);
        float r   = rsqrtf(var + 1e-5f);
        const float* gr = g + lane * 8;
        float4 g0 = *(const float4*)gr;
        float4 g1 = *(const float4*)(gr + 4);
        bf16x8 o;
        o[0] = f2bs((a.x - mu) * r * g0.x); o[1] = f2bs((a.y - mu) * r * g0.y);
        o[2] = f2bs((a.z - mu) * r * g0.z); o[3] = f2bs((a.w - mu) * r * g0.w);
        o[4] = f2bs((b.x - mu) * r * g1.x); o[5] = f2bs((b.y - mu) * r * g1.y);
        o[6] = f2bs((b.z - mu) * r * g1.z); o[7] = f2bs((b.w - mu) * r * g1.w);
        *(bf16x8*)(xnb + row * 512 + lane * 8) = o;
        return;
    }
    int bid = blockIdx.x - 2048;
    if (bid == 144){   // null K/V row (key 0, all batches)
        int b = t >> 6, d = t & 63;
        kb[((size_t)b * KCAP) * 64 + d] = f2bs(nkv[d]);
        vbt[((size_t)b * 64 + d) * KCAP + 0] = f2bs(nkv[64 + d]);
        return;
    }
    if (bid == 145){   // zero K/V pads + build bf16 mask frags (B-operand order)
        int b = t >> 6, i6 = t & 63;
        if (i6 < 63){   // kb pad rows 2049..2111 -> 0 (so pad S = q.0 = 0, P = 1, finite)
            short* kr = kb + ((size_t)b * KCAP + 2049 + i6) * 64;
            #pragma unroll
            for (int d = 0; d < 64; d += 8) *(int4*)(kr + d) = make_int4(0, 0, 0, 0);
        }
        {   // vbt pad cols 2049..2111 -> 0 (masked-by-zero V)
            short* vr = vbt + ((size_t)b * 64 + i6) * KCAP;
            for (int k = 2049; k < KCAP; k++) vr[k] = 0;
        }
        // mv frag order: lane = s*16 + hb*8 + j; key(s,hb,j) = (s>>1)*32 + 8*g + 4*hb + (j&3)
        int lane = t & 63;
        int s = lane >> 4, hb = (lane >> 3) & 1, j = lane & 7;
        int g = (j < 4) ? ((2 * s) & 3) : ((2 * s + 1) & 3);
        int kl = (s >> 1) * 32 + 8 * g + 4 * hb + (j & 3);
        const int* mrow = mask + b * Nx;
        for (int wi = 0; wi < 33; wi++){
            int gk = wi * 64 + kl;    // global key (0 = null key, always valid)
            int ok = (gk == 0) ? 1 : ((gk <= Nx) ? mrow[gk - 1] : 0);
            mvb[(size_t)b * 2112 + wi * 64 + lane] = ok ? (short)0x3F80 : (short)0;
        }
        return;
    }
    // ---- LDS-tiled transpose: 0..79 WcatT (640x512), 80..143 WoutT (512x512) ----
    bool isOut = (bid >= 80);
    int b2 = isOut ? bid - 80 : bid;
    int ntile = isOut ? (b2 & 7) : (b2 % 10);
    int ktile = isOut ? (b2 >> 3) : (b2 / 10);
    int n0 = ntile * 64, k0 = ktile * 64;
    #pragma unroll
    for (int rr = 0; rr < 64; rr += 16){   // coalesced float4 reads of W[k][n]
        int r = rr + (t >> 4), c = (t & 15) * 4;
        float4 v;
        if (isOut)            v = *(const float4*)(Wout + (size_t)(k0 + r) * 512 + n0 + c);
        else if (n0 < 512)    v = *(const float4*)(Wq   + (size_t)(k0 + r) * 512 + n0 + c);
        else                  v = *(const float4*)(Wkv  + (size_t)(k0 + r) * 128 + (n0 - 512) + c);
        ls[c + 0][r] = v.x; ls[c + 1][r] = v.y; ls[c + 2][r] = v.z; ls[c + 3][r] = v.w;
    }
    __syncthreads();
    int rn = t >> 2, kc = (t & 3) * 16;    // coalesced 32B bf16 writes of W^T[n][k]
    short tmp[16];
    #pragma unroll
    for (int j = 0; j < 16; j++) tmp[j] = f2bs(ls[rn][kc + j]);
    short* dst = (isOut ? WoutT : WcatT) + (size_t)(n0 + rn) * 512 + k0 + kc;
    *(int4*)dst       = *(int4*)&tmp[0];
    *(int4*)(dst + 8) = *(int4*)&tmp[8];
}

// ---------------- LN2: fp32 in -> fp32 out, wave per row ----------------
__global__ void __launch_bounds__(256) ln2_kernel(const float* __restrict__ z,
                                                  const float* __restrict__ g,
                                                  float* __restrict__ out){
    int w = threadIdx.x >> 6, lane = threadIdx.x & 63;
    size_t row = (size_t)blockIdx.x * 4 + w;
    const float* xr = z + row * 512 + lane * 8;
    float4 a = *(const float4*)xr;
    float4 b = *(const float4*)(xr + 4);
    float s = a.x + a.y + a.z + a.w + b.x + b.y + b.z + b.w;
    float q = a.x*a.x + a.y*a.y + a.z*a.z + a.w*a.w
            + b.x*b.x + b.y*b.y + b.z*b.z + b.w*b.w;
    #pragma unroll
    for (int m = 1; m < 64; m <<= 1){ s += __shfl_xor(s, m, 64); q += __shfl_xor(q, m, 64); }
    float mu  = s * (1.f / 512.f);
    float var = fmaxf(q * (1.f / 512.f) - mu * mu, 0.f);
    float r   = rsqrtf(var + 1e-5f);
    const float* gr = g + lane * 8;
    float4 g0 = *(const float4*)gr;
    float4 g1 = *(const float4*)(gr + 4);
    float4 o0, o1;
    o0.x = (a.x - mu) * r * g0.x; o0.y = (a.y - mu) * r * g0.y;
    o0.z = (a.z - mu) * r * g0.z; o0.w = (a.w - mu) * r * g0.w;
    o1.x = (b.x - mu) * r * g1.x; o1.y = (b.y - mu) * r * g1.y;
    o1.z = (b.z - mu) * r * g1.z; o1.w = (b.w - mu) * r * g1.w;
    float* op = out + row * 512 + lane * 8;
    *(float4*)op = o0; *(float4*)(op + 4) = o1;
}

// ---------------- GEMM QKV: 64x160 tile, grid (4,128) = 512 blocks, 2 blocks/CU ----------
// Round-16 counters: 128x160@1blk/CU = 64us at 2.9% MfmaUtil / 8.2% occupancy
// (latency-bound, 1 wave/SIMD). 64.5KB LDS -> 2 blocks/CU = 2 waves/SIMD.
// C = xn @ [Wq|Wkv]: q-scale + K scatter + masked-V^T scatter epilogue (bf16).
__global__ void __launch_bounds__(256, 2) gemm_qkv(const short* __restrict__ A,
                                                   const short* __restrict__ BwT,
                                                   const int* __restrict__ mask,
                                                   short* __restrict__ qb,
                                                   short* __restrict__ kb,
                                                   short* __restrict__ vbt){
    __shared__ short As[2][64][72];    // [buf][m][k]  18 KB
    __shared__ short Bs[2][160][72];   // [buf][n][k]  46 KB  (total 64.5 KB)
    int t = threadIdx.x;
    int lane = t & 63, w = t >> 6;
    int l16 = lane & 15, quad = lane >> 4;
    int wm = w & 1, wn = w >> 1;
    int row0 = blockIdx.y * 64, col0 = blockIdx.x * 160;
    f32x4 acc[2][5];
    #pragma unroll
    for (int i = 0; i < 2; i++)
        #pragma unroll
        for (int j = 0; j < 5; j++) acc[i][j] = (f32x4){0.f, 0.f, 0.f, 0.f};
    int ar = t >> 2, ak = (t & 3) * 16;
    const short* ap = A + (size_t)(row0 + ar) * 512 + ak;
    int4 a0 = *(const int4*)(ap);      int4 a1 = *(const int4*)(ap + 8);
    // B staging: 160 rows x 64 k = 1280 int4, 5 per thread, coalesced (idx = pass*256 + t)
    int4 pb[5];
    int brow[5], bseg[5];
    #pragma unroll
    for (int ps = 0; ps < 5; ps++){
        int idx = ps * 256 + t;
        brow[ps] = idx >> 3; bseg[ps] = (idx & 7) * 8;
        pb[ps] = *(const int4*)(BwT + (size_t)(col0 + brow[ps]) * 512 + bseg[ps]);
    }
    int p = 0;
    for (int k0 = 0; k0 < 512; k0 += 64){
        *(int4*)&As[p][ar][ak]     = a0;
        *(int4*)&As[p][ar][ak + 8] = a1;
        #pragma unroll
        for (int ps = 0; ps < 5; ps++)
            *(int4*)&Bs[p][brow[ps]][bseg[ps]] = pb[ps];
        __syncthreads();
        int kn = k0 + 64;
        if (kn < 512){   // prefetch next k-slab while computing this one
            a0 = *(const int4*)(ap + kn);
            a1 = *(const int4*)(ap + kn + 8);
            #pragma unroll
            for (int ps = 0; ps < 5; ps++)
                pb[ps] = *(const int4*)(BwT + (size_t)(col0 + brow[ps]) * 512 + kn + bseg[ps]);
        }
        #pragma unroll
        for (int ks = 0; ks < 2; ks++){
            bf16x8 af[2], bfr[5];
            #pragma unroll
            for (int mt = 0; mt < 2; mt++)
                af[mt] = *(const bf16x8*)&As[p][wm * 32 + mt * 16 + l16][ks * 32 + quad * 8];
            #pragma unroll
            for (int nt = 0; nt < 5; nt++)
                bfr[nt] = *(const bf16x8*)&Bs[p][wn * 80 + nt * 16 + l16][ks * 32 + quad * 8];
            #pragma unroll
            for (int mt = 0; mt < 2; mt++)
                #pragma unroll
                for (int nt = 0; nt < 5; nt++)
                    acc[mt][nt] = __builtin_amdgcn_mfma_f32_16x16x32_bf16(af[mt], bfr[nt], acc[mt][nt], 0, 0, 0);
        }
        p ^= 1;
    }
    #pragma unroll
    for (int mt = 0; mt < 2; mt++)
        #pragma unroll
        for (int nt = 0; nt < 5; nt++)
            #pragma unroll
            for (int r = 0; r < 4; r++){
                int row = row0 + wm * 32 + mt * 16 + quad * 4 + r;
                int col = col0 + wn * 80 + nt * 16 + l16;
                float v = acc[mt][nt][r];
                int bb = row >> 11, ii = row & 2047;
                if (col < 512){
                    qb[(size_t)row * 512 + col] = f2bs(v * QSCALE);
                } else if (col < 576){
                    kb[((size_t)bb * KCAP + ii + 1) * 64 + (col - 512)] = f2bs(v);
                } else {
                    if (!mask[bb * Nx + ii]) v = 0.f;   // masked key -> zero V column
                    vbt[((size_t)bb * 64 + (col - 576)) * KCAP + ii + 1] = f2bs(v);
                }
            }
}

// ---------------- GEMM OUT: 64x128 tile, grid (4,128) = 512 blocks, 2 blocks/CU ----------
// Old 128x128 grid(4,64)=256 blocks capped at 1 block/CU by grid size. 55.3KB LDS.
__global__ void __launch_bounds__(256, 2) gemm_out(const short* __restrict__ A,
                                                   const short* __restrict__ BwT,
                                                   float* __restrict__ C){
    __shared__ short As[2][64][72];    // 18 KB
    __shared__ short Bs[2][128][72];   // 36.9 KB (total 55.3 KB)
    int t = threadIdx.x;
    int lane = t & 63, w = t >> 6;
    int l16 = lane & 15, quad = lane >> 4;
    int wm = w & 1, wn = w >> 1;
    int row0 = blockIdx.y * 64, col0 = blockIdx.x * 128;
    f32x4 acc[2][4];
    #pragma unroll
    for (int i = 0; i < 2; i++)
        #pragma unroll
        for (int j = 0; j < 4; j++) acc[i][j] = (f32x4){0.f, 0.f, 0.f, 0.f};
    int ar = t >> 2, ak = (t & 3) * 16;   // A: 64 rows x 64 k, 16 shorts/thread
    int br = t >> 1, bk = (t & 1) * 32;   // B: 128 rows x 64 k, 32 shorts/thread
    const short* ap = A   + (size_t)(row0 + ar) * 512 + ak;
    const short* bp = BwT + (size_t)(col0 + br) * 512 + bk;
    int4 a0 = *(const int4*)(ap);      int4 a1 = *(const int4*)(ap + 8);
    int4 b0 = *(const int4*)(bp);      int4 b1 = *(const int4*)(bp + 8);
    int4 b2 = *(const int4*)(bp + 16); int4 b3 = *(const int4*)(bp + 24);
    int p = 0;
    for (int k0 = 0; k0 < 512; k0 += 64){
        *(int4*)&As[p][ar][ak]      = a0;
        *(int4*)&As[p][ar][ak + 8]  = a1;
        *(int4*)&Bs[p][br][bk]      = b0;
        *(int4*)&Bs[p][br][bk + 8]  = b1;
        *(int4*)&Bs[p][br][bk + 16] = b2;
        *(int4*)&Bs[p][br][bk + 24] = b3;
        __syncthreads();
        int kn = k0 + 64;
        if (kn < 512){
            a0 = *(const int4*)(ap + kn);      a1 = *(const int4*)(ap + kn + 8);
            b0 = *(const int4*)(bp + kn);      b1 = *(const int4*)(bp + kn + 8);
            b2 = *(const int4*)(bp + kn + 16); b3 = *(const int4*)(bp + kn + 24);
        }
        #pragma unroll
        for (int ks = 0; ks < 2; ks++){
            bf16x8 af[2], bfr[4];
            #pragma unroll
            for (int mt = 0; mt < 2; mt++)
                af[mt] = *(const bf16x8*)&As[p][wm * 32 + mt * 16 + l16][ks * 32 + quad * 8];
            #pragma unroll
            for (int nt = 0; nt < 4; nt++)
                bfr[nt] = *(const bf16x8*)&Bs[p][wn * 64 + nt * 16 + l16][ks * 32 + quad * 8];
            #pragma unroll
            for (int mt = 0; mt < 2; mt++)
                #pragma unroll
                for (int nt = 0; nt < 4; nt++)
                    acc[mt][nt] = __builtin_amdgcn_mfma_f32_16x16x32_bf16(af[mt], bfr[nt], acc[mt][nt], 0, 0, 0);
        }
        p ^= 1;
    }
    #pragma unroll
    for (int mt = 0; mt < 2; mt++)
        #pragma unroll
        for (int nt = 0; nt < 4; nt++)
            #pragma unroll
            for (int r = 0; r < 4; r++){
                int row = row0 + wm * 32 + mt * 16 + quad * 4 + r;
                int col = col0 + wn * 64 + nt * 16 + l16;
                C[(size_t)row * 512 + col] = acc[mt][nt][r];
            }
}

// ---------------- MFMA attention v10 (VERIFIED BEST: 48.8 us): mask-free loop + rotation ----
// Grid (128 row-tiles, 4 batches). Block = 16 q-rows x 8 heads; wave = 2 heads. KVBLK=64.
// Per-block tile-order rotation phase-staggers co-resident blocks (+8% measured).
// Masking out of the loop (zeroed V cols + maskvec L). Key-split (v11/v12) measured worse.
__global__ void __launch_bounds__(256, 2) attn_kernel(const short* __restrict__ qb,
                                                      const short* __restrict__ kb,
                                                      const short* __restrict__ vbt,
                                                      const short* __restrict__ mvb,
                                                      short* __restrict__ ob){
    __shared__ short Ks[2][64][72];   // [buf][key][d]
    __shared__ short Vt[2][64][72];   // [buf][d][key], key cols bit2<->bit3 swapped
    int t = threadIdx.x;
    int lane = t & 63, w = t >> 6;
    int n32 = lane & 31, hb = lane >> 5;
    int b = blockIdx.y, i0 = blockIdx.x * 16;
    int head = 2 * w + (n32 >> 4), row = i0 + (n32 & 15);
    bf16x8 qf[4];
    {
        const short* qp = qb + ((size_t)(b * Nx + row)) * 512 + head * 64 + hb * 8;
        #pragma unroll
        for (int ks = 0; ks < 4; ks++) qf[ks] = *(const bf16x8*)(qp + ks * 16);
    }
    f32x16 oacc[2], lacc;
    #pragma unroll
    for (int j = 0; j < 16; j++){ oacc[0][j] = 0.f; oacc[1][j] = 0.f; lacc[j] = 0.f; }

    int skey = t >> 2, sd = (t & 3) * 16;   // K staging: 64 keys x 64 d
    int vd   = t >> 2, vk = (t & 3) * 16;   // V staging: 64 d x 64 keys
    const short* kgp = kb  + (size_t)b * KCAP * 64 + skey * 64 + sd;
    const short* vgp = vbt + ((size_t)b * 64 + vd) * KCAP + vk;
    const short* mvq = mvb + (size_t)b * 2112 + hb * 8;   // mask frags, B-operand order

    int off = (blockIdx.x + 8 * blockIdx.y) % 33;

    int jt = off;
    int4 pk0 = *(const int4*)(kgp + (size_t)jt * 4096);
    int4 pk1 = *(const int4*)(kgp + (size_t)jt * 4096 + 8);
    int4 pv0 = *(const int4*)(vgp + jt * 64);
    int4 pv1 = *(const int4*)(vgp + jt * 64 + 8);

    int p = 0;
    for (int it = 0; it < 33; ++it){
        *(int4*)&Ks[p][skey][sd]     = pk0;
        *(int4*)&Ks[p][skey][sd + 8] = pk1;
        *(int4*)&Vt[p][vd][vk]       = make_int4(pv0.x, pv0.y, pv1.x, pv1.y);
        *(int4*)&Vt[p][vd][vk + 8]   = make_int4(pv0.z, pv0.w, pv1.z, pv1.w);
        __syncthreads();
        bf16x8 mvf[4];
        #pragma unroll
        for (int s = 0; s < 4; s++) mvf[s] = *(const bf16x8*)(mvq + jt * 64 + s * 16);
        int jn = jt + 1; if (jn == 33) jn = 0;
        if (it + 1 < 33){
            pk0 = *(const int4*)(kgp + (size_t)jn * 4096);
            pk1 = *(const int4*)(kgp + (size_t)jn * 4096 + 8);
            pv0 = *(const int4*)(vgp + jn * 64);
            pv1 = *(const int4*)(vgp + jn * 64 + 8);
        }
        f32x16 sf[2];
        #pragma unroll
        for (int i = 0; i < 2; i++)
            #pragma unroll
            for (int j = 0; j < 16; j++) sf[i][j] = 0.f;
        __builtin_amdgcn_s_setprio(1);
        #pragma unroll
        for (int ks = 0; ks < 4; ks++){
            #pragma unroll
            for (int kt = 0; kt < 2; kt++){
                bf16x8 kf = *(const bf16x8*)&Ks[p][kt * 32 + n32][ks * 16 + hb * 8];
                sf[kt] = __builtin_amdgcn_mfma_f32_32x32x16_bf16(kf, qf[ks], sf[kt], 0, 0, 0);
            }
        }
        __builtin_amdgcn_s_setprio(0);
        unsigned pg[8][2];
        #pragma unroll
        for (int kt = 0; kt < 2; kt++){
            #pragma unroll
            for (int g4 = 0; g4 < 4; g4++){
                float pr[4];
                #pragma unroll
                for (int tt = 0; tt < 4; tt++)
                    pr[tt] = __builtin_amdgcn_exp2f(sf[kt][g4 * 4 + tt]);
                pg[kt * 4 + g4][0] = pack_trunc(pr[0], pr[1]);
                pg[kt * 4 + g4][1] = pack_trunc(pr[2], pr[3]);
            }
        }
        __builtin_amdgcn_s_setprio(1);
        #pragma unroll
        for (int s = 0; s < 4; s++){
            bf16x8 pa = __builtin_bit_cast(bf16x8,
                (u32x4){pg[2 * s][0], pg[2 * s][1], pg[2 * s + 1][0], pg[2 * s + 1][1]});
            lacc = __builtin_amdgcn_mfma_f32_32x32x16_bf16(pa, mvf[s], lacc, 0, 0, 0);
            #pragma unroll
            for (int nt = 0; nt < 2; nt++){
                bf16x8 vf = *(const bf16x8*)&Vt[p][nt * 32 + n32][s * 16 + hb * 8];
                oacc[nt] = __builtin_amdgcn_mfma_f32_32x32x16_bf16(pa, vf, oacc[nt], 0, 0, 0);
            }
        }
        __builtin_amdgcn_s_setprio(0);
        p ^= 1;
        jt = jn;
    }
    #pragma unroll
    for (int r = 0; r < 16; r++){
        float linv = 1.f / lacc[r];
        int hr = (r & 3) + 8 * (r >> 2) + 4 * hb;
        int grow = i0 + (hr & 15);
        int ghead = 2 * w + (hr >> 4);
        short* op = ob + ((size_t)(b * Nx + grow)) * 512 + ghead * 64 + n32;
        op[0]  = f2bs(oacc[0][r] * linv);
        op[32] = f2bs(oacc[1][r] * linv);
    }
}

extern "C" void kernel_launch(void* const* d_in, const int* in_sizes, int n_in,
                              void* d_out, int out_size, void* d_ws, size_t ws_size,
                              hipStream_t stream){
    const float* x     = (const float*)d_in[0];
    const int*   mask  = (const int*)  d_in[1];
    const float* gamma = (const float*)d_in[2];
    const float* Wq    = (const float*)d_in[3];
    const float* Wkv   = (const float*)d_in[4];
    const float* nkv   = (const float*)d_in[5];
    const float* Wout  = (const float*)d_in[6];
    const float* og    = (const float*)d_in[7];
    float* out = (float*)d_out;

    short* xnb   = (short*)d_ws;                 // 4194304 shorts
    short* qb    = xnb + (size_t)4194304;        // 4194304
    short* kb    = qb  + (size_t)4194304;        // 4*KCAP*64 = 540672 (pads zeroed)
    short* vbt   = kb  + (size_t)540672;         // 540672 (pads zeroed)
    short* ob    = vbt + (size_t)540672;         // 4194304
    short* WcatT = ob  + (size_t)4194304;        // 327680
    short* WoutT = WcatT + (size_t)327680;       // 262144
    short* mvb   = WoutT + (size_t)262144;       // 4*33*64 = 8448 (bf16 mask frags)
    float* zb    = (float*)d_ws;                 // aliases xnb+qb (both dead by gemm_out)

    ln1_prep_kernel<<<2194, 256, 0, stream>>>(x, gamma, xnb, Wq, Wkv, Wout, nkv, mask,
                                              WcatT, WoutT, kb, vbt, mvb);
    gemm_qkv    <<<dim3(4, 128), 256, 0, stream>>>(xnb, WcatT, mask, qb, kb, vbt);
    attn_kernel <<<dim3(128, 4), 256, 0, stream>>>(qb, kb, vbt, mvb, ob);
    gemm_out    <<<dim3(4, 128), 256, 0, stream>>>(ob, WoutT, zb);
    ln2_kernel  <<<2048, 256, 0, stream>>>(zb, og, out);
}

// Round 22
// 192.009 us; speedup vs baseline: 1.2446x; 1.0016x over previous
//
#include <hip/hip_runtime.h>

typedef __attribute__((ext_vector_type(8)))  short bf16x8;   // MFMA A/B frag (4 VGPRs)
typedef __attribute__((ext_vector_type(4)))  float f32x4;    // 16x16 C/D frag
typedef __attribute__((ext_vector_type(16))) float f32x16;   // 32x32 C/D frag
typedef __attribute__((ext_vector_type(4)))  unsigned u32x4;

#define Nx 2048
#define CTXx 2049
#define KCAP 2112          // 2049 real keys + pad; pad K rows/V cols ZEROED (P=1 x V=0 = 0)
#define QSCALE 0.18033688f // 0.125 * log2(e): softmax computed as 2^(S*log2e) = e^S

__device__ __forceinline__ short f2bs(float x){   // float -> bf16 bits (RNE)
    unsigned u = __builtin_bit_cast(unsigned, x);
    u = (u + 0x7fffu + ((u >> 16) & 1u)) >> 16;
    return (short)u;
}
// truncating pack: (hi16 of b)<<16 | (hi16 of a) — 1 v_perm_b32
__device__ __forceinline__ unsigned pack_trunc(float a, float b){
    return __builtin_amdgcn_perm(__builtin_bit_cast(unsigned, b),
                                 __builtin_bit_cast(unsigned, a), 0x07060302u);
}

// ---------------- fused LN1 (blocks 0..2047) + weight prep (2048..2193) ----------------
__global__ void __launch_bounds__(256) ln1_prep_kernel(const float* __restrict__ x,
                                                       const float* __restrict__ g,
                                                       short* __restrict__ xnb,
                                                       const float* __restrict__ Wq,
                                                       const float* __restrict__ Wkv,
                                                       const float* __restrict__ Wout,
                                                       const float* __restrict__ nkv,
                                                       const int* __restrict__ mask,
                                                       short* __restrict__ WcatT,
                                                       short* __restrict__ WoutT,
                                                       short* __restrict__ kb,
                                                       short* __restrict__ vbt,
                                                       short* __restrict__ mvb){
    __shared__ float ls[64][65];
    int t = threadIdx.x;
    if (blockIdx.x < 2048){    // ---- LN1: wave per row, fp32 -> bf16 ----
        int w = t >> 6, lane = t & 63;
        size_t row = (size_t)blockIdx.x * 4 + w;
        const float* xr = x + row * 512 + lane * 8;
        float4 a = *(const float4*)xr;
        float4 b = *(const float4*)(xr + 4);
        float s = a.x + a.y + a.z + a.w + b.x + b.y + b.z + b.w;
        float q = a.x*a.x + a.y*a.y + a.z*a.z + a.w*a.w
                + b.x*b.x + b.y*b.y + b.z*b.z + b.w*b.w;
        #pragma unroll
        for (int m = 1; m < 64; m <<= 1){ s += __shfl_xor(s, m, 64); q += __shfl_xor(q, m, 64); }
        float mu  = s * (1.f / 512.f);
        float var = fmaxf(q * (1.f / 512.f) - mu * mu, 0.f);
        float r   = rsqrtf(var + 1e-5f);
        const float* gr = g + lane * 8;
        float4 g0 = *(const float4*)gr;
        float4 g1 = *(const float4*)(gr + 4);
        bf16x8 o;
        o[0] = f2bs((a.x - mu) * r * g0.x); o[1] = f2bs((a.y - mu) * r * g0.y);
        o[2] = f2bs((a.z - mu) * r * g0.z); o[3] = f2bs((a.w - mu) * r * g0.w);
        o[4] = f2bs((b.x - mu) * r * g1.x); o[5] = f2bs((b.y - mu) * r * g1.y);
        o[6] = f2bs((b.z - mu) * r * g1.z); o[7] = f2bs((b.w - mu) * r * g1.w);
        *(bf16x8*)(xnb + row * 512 + lane * 8) = o;
        return;
    }
    int bid = blockIdx.x - 2048;
    if (bid == 144){   // null K/V row (key 0, all batches)
        int b = t >> 6, d = t & 63;
        kb[((size_t)b * KCAP) * 64 + d] = f2bs(nkv[d]);
        vbt[((size_t)b * 64 + d) * KCAP + 0] = f2bs(nkv[64 + d]);
        return;
    }
    if (bid == 145){   // zero K/V pads + build bf16 mask frags (B-operand order)
        int b = t >> 6, i6 = t & 63;
        if (i6 < 63){   // kb pad rows 2049..2111 -> 0 (so pad S = q.0 = 0, P = 1, finite)
            short* kr = kb + ((size_t)b * KCAP + 2049 + i6) * 64;
            #pragma unroll
            for (int d = 0; d < 64; d += 8) *(int4*)(kr + d) = make_int4(0, 0, 0, 0);
        }
        {   // vbt pad cols 2049..2111 -> 0 (masked-by-zero V)
            short* vr = vbt + ((size_t)b * 64 + i6) * KCAP;
            for (int k = 2049; k < KCAP; k++) vr[k] = 0;
        }
        // mv frag order: lane = s*16 + hb*8 + j; key(s,hb,j) = (s>>1)*32 + 8*g + 4*hb + (j&3)
        int lane = t & 63;
        int s = lane >> 4, hb = (lane >> 3) & 1, j = lane & 7;
        int g = (j < 4) ? ((2 * s) & 3) : ((2 * s + 1) & 3);
        int kl = (s >> 1) * 32 + 8 * g + 4 * hb + (j & 3);
        const int* mrow = mask + b * Nx;
        for (int wi = 0; wi < 33; wi++){
            int gk = wi * 64 + kl;    // global key (0 = null key, always valid)
            int ok = (gk == 0) ? 1 : ((gk <= Nx) ? mrow[gk - 1] : 0);
            mvb[(size_t)b * 2112 + wi * 64 + lane] = ok ? (short)0x3F80 : (short)0;
        }
        return;
    }
    // ---- LDS-tiled transpose: 0..79 WcatT (640x512), 80..143 WoutT (512x512) ----
    bool isOut = (bid >= 80);
    int b2 = isOut ? bid - 80 : bid;
    int ntile = isOut ? (b2 & 7) : (b2 % 10);
    int ktile = isOut ? (b2 >> 3) : (b2 / 10);
    int n0 = ntile * 64, k0 = ktile * 64;
    #pragma unroll
    for (int rr = 0; rr < 64; rr += 16){   // coalesced float4 reads of W[k][n]
        int r = rr + (t >> 4), c = (t & 15) * 4;
        float4 v;
        if (isOut)            v = *(const float4*)(Wout + (size_t)(k0 + r) * 512 + n0 + c);
        else if (n0 < 512)    v = *(const float4*)(Wq   + (size_t)(k0 + r) * 512 + n0 + c);
        else                  v = *(const float4*)(Wkv  + (size_t)(k0 + r) * 128 + (n0 - 512) + c);
        ls[c + 0][r] = v.x; ls[c + 1][r] = v.y; ls[c + 2][r] = v.z; ls[c + 3][r] = v.w;
    }
    __syncthreads();
    int rn = t >> 2, kc = (t & 3) * 16;    // coalesced 32B bf16 writes of W^T[n][k]
    short tmp[16];
    #pragma unroll
    for (int j = 0; j < 16; j++) tmp[j] = f2bs(ls[rn][kc + j]);
    short* dst = (isOut ? WoutT : WcatT) + (size_t)(n0 + rn) * 512 + k0 + kc;
    *(int4*)dst       = *(int4*)&tmp[0];
    *(int4*)(dst + 8) = *(int4*)&tmp[8];
}

// ---------------- LN2: fp32 in -> fp32 out, wave per row ----------------
__global__ void __launch_bounds__(256) ln2_kernel(const float* __restrict__ z,
                                                  const float* __restrict__ g,
                                                  float* __restrict__ out){
    int w = threadIdx.x >> 6, lane = threadIdx.x & 63;
    size_t row = (size_t)blockIdx.x * 4 + w;
    const float* xr = z + row * 512 + lane * 8;
    float4 a = *(const float4*)xr;
    float4 b = *(const float4*)(xr + 4);
    float s = a.x + a.y + a.z + a.w + b.x + b.y + b.z + b.w;
    float q = a.x*a.x + a.y*a.y + a.z*a.z + a.w*a.w
            + b.x*b.x + b.y*b.y + b.z*b.z + b.w*b.w;
    #pragma unroll
    for (int m = 1; m < 64; m <<= 1){ s += __shfl_xor(s, m, 64); q += __shfl_xor(q, m, 64); }
    float mu  = s * (1.f / 512.f);
    float var = fmaxf(q * (1.f / 512.f) - mu * mu, 0.f);
    float r   = rsqrtf(var + 1e-5f);
    const float* gr = g + lane * 8;
    float4 g0 = *(const float4*)gr;
    float4 g1 = *(const float4*)(gr + 4);
    float4 o0, o1;
    o0.x = (a.x - mu) * r * g0.x; o0.y = (a.y - mu) * r * g0.y;
    o0.z = (a.z - mu) * r * g0.z; o0.w = (a.w - mu) * r * g0.w;
    o1.x = (b.x - mu) * r * g1.x; o1.y = (b.y - mu) * r * g1.y;
    o1.z = (b.z - mu) * r * g1.z; o1.w = (b.w - mu) * r * g1.w;
    float* op = out + row * 512 + lane * 8;
    *(float4*)op = o0; *(float4*)(op + 4) = o1;
}

// ---------------- GEMM QKV: 64x80 tile, grid (8,128) = 1024 blocks, 3 blocks/CU ----------
// Round-19: 64x160@2blk/CU dropped below 48us (was 64 at 1blk). 40.5KB LDS -> 3 blocks/CU
// = 3 waves/SIMD for deeper latency hiding. Wave = 16 rows x 80 cols (acc[5]).
// C = xn @ [Wq|Wkv]: q-scale + K scatter + masked-V^T scatter epilogue (bf16).
__global__ void __launch_bounds__(256, 3) gemm_qkv(const short* __restrict__ A,
                                                   const short* __restrict__ BwT,
                                                   const int* __restrict__ mask,
                                                   short* __restrict__ qb,
                                                   short* __restrict__ kb,
                                                   short* __restrict__ vbt){
    __shared__ short As[2][64][72];    // 18 KB
    __shared__ short Bs[2][80][72];    // 22.5 KB  (total 40.5 KB -> 3 blocks/CU)
    int t = threadIdx.x;
    int lane = t & 63, w = t >> 6;
    int l16 = lane & 15, quad = lane >> 4;
    int row0 = blockIdx.y * 64, col0 = blockIdx.x * 80;
    f32x4 acc[5];
    #pragma unroll
    for (int j = 0; j < 5; j++) acc[j] = (f32x4){0.f, 0.f, 0.f, 0.f};
    int ar = t >> 2, ak = (t & 3) * 16;
    const short* ap = A + (size_t)(row0 + ar) * 512 + ak;
    int4 a0 = *(const int4*)(ap);      int4 a1 = *(const int4*)(ap + 8);
    // B staging: 80 rows x 64 k = 640 int4; ps0: rows 0..31, ps1: 32..63, ps2 (t<128): 64..79
    bool bv2 = (t < 128);
    int brow0 = (t >> 3),      bseg = (t & 7) * 8;
    int brow1 = 32 + (t >> 3);
    int brow2 = 64 + (t >> 3);            // valid only when bv2
    int4 pb0 = *(const int4*)(BwT + (size_t)(col0 + brow0) * 512 + bseg);
    int4 pb1 = *(const int4*)(BwT + (size_t)(col0 + brow1) * 512 + bseg);
    int4 pb2 = make_int4(0, 0, 0, 0);
    if (bv2) pb2 = *(const int4*)(BwT + (size_t)(col0 + brow2) * 512 + bseg);
    int p = 0;
    for (int k0 = 0; k0 < 512; k0 += 64){
        *(int4*)&As[p][ar][ak]     = a0;
        *(int4*)&As[p][ar][ak + 8] = a1;
        *(int4*)&Bs[p][brow0][bseg] = pb0;
        *(int4*)&Bs[p][brow1][bseg] = pb1;
        if (bv2) *(int4*)&Bs[p][brow2][bseg] = pb2;
        __syncthreads();
        int kn = k0 + 64;
        if (kn < 512){   // prefetch next k-slab while computing this one
            a0 = *(const int4*)(ap + kn);
            a1 = *(const int4*)(ap + kn + 8);
            pb0 = *(const int4*)(BwT + (size_t)(col0 + brow0) * 512 + kn + bseg);
            pb1 = *(const int4*)(BwT + (size_t)(col0 + brow1) * 512 + kn + bseg);
            if (bv2) pb2 = *(const int4*)(BwT + (size_t)(col0 + brow2) * 512 + kn + bseg);
        }
        #pragma unroll
        for (int ks = 0; ks < 2; ks++){
            bf16x8 af = *(const bf16x8*)&As[p][w * 16 + l16][ks * 32 + quad * 8];
            bf16x8 bfr[5];
            #pragma unroll
            for (int nt = 0; nt < 5; nt++)
                bfr[nt] = *(const bf16x8*)&Bs[p][nt * 16 + l16][ks * 32 + quad * 8];
            #pragma unroll
            for (int nt = 0; nt < 5; nt++)
                acc[nt] = __builtin_amdgcn_mfma_f32_16x16x32_bf16(af, bfr[nt], acc[nt], 0, 0, 0);
        }
        p ^= 1;
    }
    #pragma unroll
    for (int nt = 0; nt < 5; nt++)
        #pragma unroll
        for (int r = 0; r < 4; r++){
            int row = row0 + w * 16 + quad * 4 + r;
            int col = col0 + nt * 16 + l16;
            float v = acc[nt][r];
            int bb = row >> 11, ii = row & 2047;
            if (col < 512){
                qb[(size_t)row * 512 + col] = f2bs(v * QSCALE);
            } else if (col < 576){
                kb[((size_t)bb * KCAP + ii + 1) * 64 + (col - 512)] = f2bs(v);
            } else {
                if (!mask[bb * Nx + ii]) v = 0.f;   // masked key -> zero V column
                vbt[((size_t)bb * 64 + (col - 576)) * KCAP + ii + 1] = f2bs(v);
            }
        }
}

// ---------------- GEMM OUT: 64x64 tile, grid (8,128) = 1024 blocks, 4 blocks/CU ----------
// 36.9KB LDS -> 4 blocks/CU = 4 waves/SIMD. Wave = 32x32 quadrant (acc[2][2]).
__global__ void __launch_bounds__(256, 4) gemm_out(const short* __restrict__ A,
                                                   const short* __restrict__ BwT,
                                                   float* __restrict__ C){
    __shared__ short As[2][64][72];    // 18 KB
    __shared__ short Bs[2][64][72];    // 18 KB (total 36.9 KB)
    int t = threadIdx.x;
    int lane = t & 63, w = t >> 6;
    int l16 = lane & 15, quad = lane >> 4;
    int wm = w & 1, wn = w >> 1;
    int row0 = blockIdx.y * 64, col0 = blockIdx.x * 64;
    f32x4 acc[2][2];
    #pragma unroll
    for (int i = 0; i < 2; i++)
        #pragma unroll
        for (int j = 0; j < 2; j++) acc[i][j] = (f32x4){0.f, 0.f, 0.f, 0.f};
    int ar = t >> 2, ak = (t & 3) * 16;   // 64 rows x 64 k, 16 shorts/thread (A and B alike)
    const short* ap = A   + (size_t)(row0 + ar) * 512 + ak;
    const short* bp = BwT + (size_t)(col0 + ar) * 512 + ak;
    int4 a0 = *(const int4*)(ap);  int4 a1 = *(const int4*)(ap + 8);
    int4 b0 = *(const int4*)(bp);  int4 b1 = *(const int4*)(bp + 8);
    int p = 0;
    for (int k0 = 0; k0 < 512; k0 += 64){
        *(int4*)&As[p][ar][ak]     = a0;
        *(int4*)&As[p][ar][ak + 8] = a1;
        *(int4*)&Bs[p][ar][ak]     = b0;
        *(int4*)&Bs[p][ar][ak + 8] = b1;
        __syncthreads();
        int kn = k0 + 64;
        if (kn < 512){
            a0 = *(const int4*)(ap + kn);  a1 = *(const int4*)(ap + kn + 8);
            b0 = *(const int4*)(bp + kn);  b1 = *(const int4*)(bp + kn + 8);
        }
        #pragma unroll
        for (int ks = 0; ks < 2; ks++){
            bf16x8 af[2], bfr[2];
            #pragma unroll
            for (int mt = 0; mt < 2; mt++)
                af[mt] = *(const bf16x8*)&As[p][wm * 32 + mt * 16 + l16][ks * 32 + quad * 8];
            #pragma unroll
            for (int nt = 0; nt < 2; nt++)
                bfr[nt] = *(const bf16x8*)&Bs[p][wn * 32 + nt * 16 + l16][ks * 32 + quad * 8];
            #pragma unroll
            for (int mt = 0; mt < 2; mt++)
                #pragma unroll
                for (int nt = 0; nt < 2; nt++)
                    acc[mt][nt] = __builtin_amdgcn_mfma_f32_16x16x32_bf16(af[mt], bfr[nt], acc[mt][nt], 0, 0, 0);
        }
        p ^= 1;
    }
    #pragma unroll
    for (int mt = 0; mt < 2; mt++)
        #pragma unroll
        for (int nt = 0; nt < 2; nt++)
            #pragma unroll
            for (int r = 0; r < 4; r++){
                int row = row0 + wm * 32 + mt * 16 + quad * 4 + r;
                int col = col0 + wn * 32 + nt * 16 + l16;
                C[(size_t)row * 512 + col] = acc[mt][nt][r];
            }
}

// ---------------- MFMA attention v10 (VERIFIED BEST: 48.8 us): mask-free loop + rotation ----
// Grid (128 row-tiles, 4 batches). Block = 16 q-rows x 8 heads; wave = 2 heads. KVBLK=64.
// Per-block tile-order rotation phase-staggers co-resident blocks (+8% measured).
// Masking out of the loop (zeroed V cols + maskvec L). Key-split (v11/v12) measured worse.
__global__ void __launch_bounds__(256, 2) attn_kernel(const short* __restrict__ qb,
                                                      const short* __restrict__ kb,
                                                      const short* __restrict__ vbt,
                                                      const short* __restrict__ mvb,
                                                      short* __restrict__ ob){
    __shared__ short Ks[2][64][72];   // [buf][key][d]
    __shared__ short Vt[2][64][72];   // [buf][d][key], key cols bit2<->bit3 swapped
    int t = threadIdx.x;
    int lane = t & 63, w = t >> 6;
    int n32 = lane & 31, hb = lane >> 5;
    int b = blockIdx.y, i0 = blockIdx.x * 16;
    int head = 2 * w + (n32 >> 4), row = i0 + (n32 & 15);
    bf16x8 qf[4];
    {
        const short* qp = qb + ((size_t)(b * Nx + row)) * 512 + head * 64 + hb * 8;
        #pragma unroll
        for (int ks = 0; ks < 4; ks++) qf[ks] = *(const bf16x8*)(qp + ks * 16);
    }
    f32x16 oacc[2], lacc;
    #pragma unroll
    for (int j = 0; j < 16; j++){ oacc[0][j] = 0.f; oacc[1][j] = 0.f; lacc[j] = 0.f; }

    int skey = t >> 2, sd = (t & 3) * 16;   // K staging: 64 keys x 64 d
    int vd   = t >> 2, vk = (t & 3) * 16;   // V staging: 64 d x 64 keys
    const short* kgp = kb  + (size_t)b * KCAP * 64 + skey * 64 + sd;
    const short* vgp = vbt + ((size_t)b * 64 + vd) * KCAP + vk;
    const short* mvq = mvb + (size_t)b * 2112 + hb * 8;   // mask frags, B-operand order

    int off = (blockIdx.x + 8 * blockIdx.y) % 33;

    int jt = off;
    int4 pk0 = *(const int4*)(kgp + (size_t)jt * 4096);
    int4 pk1 = *(const int4*)(kgp + (size_t)jt * 4096 + 8);
    int4 pv0 = *(const int4*)(vgp + jt * 64);
    int4 pv1 = *(const int4*)(vgp + jt * 64 + 8);

    int p = 0;
    for (int it = 0; it < 33; ++it){
        *(int4*)&Ks[p][skey][sd]     = pk0;
        *(int4*)&Ks[p][skey][sd + 8] = pk1;
        *(int4*)&Vt[p][vd][vk]       = make_int4(pv0.x, pv0.y, pv1.x, pv1.y);
        *(int4*)&Vt[p][vd][vk + 8]   = make_int4(pv0.z, pv0.w, pv1.z, pv1.w);
        __syncthreads();
        bf16x8 mvf[4];
        #pragma unroll
        for (int s = 0; s < 4; s++) mvf[s] = *(const bf16x8*)(mvq + jt * 64 + s * 16);
        int jn = jt + 1; if (jn == 33) jn = 0;
        if (it + 1 < 33){
            pk0 = *(const int4*)(kgp + (size_t)jn * 4096);
            pk1 = *(const int4*)(kgp + (size_t)jn * 4096 + 8);
            pv0 = *(const int4*)(vgp + jn * 64);
            pv1 = *(const int4*)(vgp + jn * 64 + 8);
        }
        f32x16 sf[2];
        #pragma unroll
        for (int i = 0; i < 2; i++)
            #pragma unroll
            for (int j = 0; j < 16; j++) sf[i][j] = 0.f;
        __builtin_amdgcn_s_setprio(1);
        #pragma unroll
        for (int ks = 0; ks < 4; ks++){
            #pragma unroll
            for (int kt = 0; kt < 2; kt++){
                bf16x8 kf = *(const bf16x8*)&Ks[p][kt * 32 + n32][ks * 16 + hb * 8];
                sf[kt] = __builtin_amdgcn_mfma_f32_32x32x16_bf16(kf, qf[ks], sf[kt], 0, 0, 0);
            }
        }
        __builtin_amdgcn_s_setprio(0);
        unsigned pg[8][2];
        #pragma unroll
        for (int kt = 0; kt < 2; kt++){
            #pragma unroll
            for (int g4 = 0; g4 < 4; g4++){
                float pr[4];
                #pragma unroll
                for (int tt = 0; tt < 4; tt++)
                    pr[tt] = __builtin_amdgcn_exp2f(sf[kt][g4 * 4 + tt]);
                pg[kt * 4 + g4][0] = pack_trunc(pr[0], pr[1]);
                pg[kt * 4 + g4][1] = pack_trunc(pr[2], pr[3]);
            }
        }
        __builtin_amdgcn_s_setprio(1);
        #pragma unroll
        for (int s = 0; s < 4; s++){
            bf16x8 pa = __builtin_bit_cast(bf16x8,
                (u32x4){pg[2 * s][0], pg[2 * s][1], pg[2 * s + 1][0], pg[2 * s + 1][1]});
            lacc = __builtin_amdgcn_mfma_f32_32x32x16_bf16(pa, mvf[s], lacc, 0, 0, 0);
            #pragma unroll
            for (int nt = 0; nt < 2; nt++){
                bf16x8 vf = *(const bf16x8*)&Vt[p][nt * 32 + n32][s * 16 + hb * 8];
                oacc[nt] = __builtin_amdgcn_mfma_f32_32x32x16_bf16(pa, vf, oacc[nt], 0, 0, 0);
            }
        }
        __builtin_amdgcn_s_setprio(0);
        p ^= 1;
        jt = jn;
    }
    #pragma unroll
    for (int r = 0; r < 16; r++){
        float linv = 1.f / lacc[r];
        int hr = (r & 3) + 8 * (r >> 2) + 4 * hb;
        int grow = i0 + (hr & 15);
        int ghead = 2 * w + (hr >> 4);
        short* op = ob + ((size_t)(b * Nx + grow)) * 512 + ghead * 64 + n32;
        op[0]  = f2bs(oacc[0][r] * linv);
        op[32] = f2bs(oacc[1][r] * linv);
    }
}

extern "C" void kernel_launch(void* const* d_in, const int* in_sizes, int n_in,
                              void* d_out, int out_size, void* d_ws, size_t ws_size,
                              hipStream_t stream){
    const float* x     = (const float*)d_in[0];
    const int*   mask  = (const int*)  d_in[1];
    const float* gamma = (const float*)d_in[2];
    const float* Wq    = (const float*)d_in[3];
    const float* Wkv   = (const float*)d_in[4];
    const float* nkv   = (const float*)d_in[5];
    const float* Wout  = (const float*)d_in[6];
    const float* og    = (const float*)d_in[7];
    float* out = (float*)d_out;

    short* xnb   = (short*)d_ws;                 // 4194304 shorts
    short* qb    = xnb + (size_t)4194304;        // 4194304
    short* kb    = qb  + (size_t)4194304;        // 4*KCAP*64 = 540672 (pads zeroed)
    short* vbt   = kb  + (size_t)540672;         // 540672 (pads zeroed)
    short* ob    = vbt + (size_t)540672;         // 4194304
    short* WcatT = ob  + (size_t)4194304;        // 327680
    short* WoutT = WcatT + (size_t)327680;       // 262144
    short* mvb   = WoutT + (size_t)262144;       // 4*33*64 = 8448 (bf16 mask frags)
    float* zb    = (float*)d_ws;                 // aliases xnb+qb (both dead by gemm_out)

    ln1_prep_kernel<<<2194, 256, 0, stream>>>(x, gamma, xnb, Wq, Wkv, Wout, nkv, mask,
                                              WcatT, WoutT, kb, vbt, mvb);
    gemm_qkv    <<<dim3(8, 128), 256, 0, stream>>>(xnb, WcatT, mask, qb, kb, vbt);
    attn_kernel <<<dim3(128, 4), 256, 0, stream>>>(qb, kb, vbt, mvb, ob);
    gemm_out    <<<dim3(8, 128), 256, 0, stream>>>(ob, WoutT, zb);
    ln2_kernel  <<<2048, 256, 0, stream>>>(zb, og, out);
}